// Round 8
// baseline (1160.943 us; speedup 1.0000x reference)
//
#include <hip/hip_runtime.h>

// GCN 2-layer: per layer h = X@W; out[i] = b + dinv[i]^2*h[i] + sum_{e:dst=i} dinv[src]*dinv[i]*h[src]
// N=100000 nodes, E=1200000 edges, C=64 channels, fp32 throughout.
// R6 kept: dinv[src] folded into gemm epilogue; dinv[dst] applied once in aggregate;
//          csrc stores src only (4 B/edge).
// R7: two-phase XCD-local scatter (bucket = 256-node dst range; pass B bins edges
//     with team = bucket&7 == blockIdx&7 so each bucket's lines have single-XCD
//     writers; pass C fine-scatters per bucket with LDS cursors).
// R8: FIX R7 crash — binC's rp[256] (bucket-end row pointer) was never loaded when
//     nn==256 (guard `tid <= nn` with 256 threads covers only 0..255) -> garbage
//     loop bound -> OOB writes -> abort. Strided load now covers all nn+1 entries.

#define NCH 64
#define XS_STRIDE 68  // 64 + 4 pad: keeps b128 16B alignment; 4-row spacing -> bank+16 (2-way, free)

// counts[d] = #edges with dst==d
__global__ void hist_kernel(const int* __restrict__ dst, int* __restrict__ counts, int E) {
    int e = blockIdx.x * blockDim.x + threadIdx.x;
    if (e < E) atomicAdd(&counts[dst[e]], 1);
}

// ---------------- exclusive scan (3-phase), chunk = 1024; dinv fused ----------------
__global__ __launch_bounds__(256) void scanA_kernel(const int* __restrict__ counts,
                                                    int* __restrict__ rowp,
                                                    int* __restrict__ bsums,
                                                    float* __restrict__ dinv, int n) {
    __shared__ int sh[256];
    int tid = threadIdx.x;
    int base = blockIdx.x * 1024;
    int v[4];
    int ts = 0;
#pragma unroll
    for (int j = 0; j < 4; j++) {
        int idx = base + tid * 4 + j;
        int c = (idx < n) ? counts[idx] : 0;
        v[j] = c; ts += c;
        if (idx < n) dinv[idx] = rsqrtf((float)(c + 1));  // +1 self loop
    }
    sh[tid] = ts; __syncthreads();
    for (int off = 1; off < 256; off <<= 1) {
        int t = (tid >= off) ? sh[tid - off] : 0;
        __syncthreads();
        sh[tid] += t;
        __syncthreads();
    }
    int run = sh[tid] - ts;  // exclusive offset within chunk
#pragma unroll
    for (int j = 0; j < 4; j++) {
        run += v[j];
        int idx = base + tid * 4 + j;
        if (idx < n) rowp[idx + 1] = run;  // inclusive-within-chunk at [idx+1]
    }
    if (tid == 255) bsums[blockIdx.x] = sh[255];
}

__global__ __launch_bounds__(128) void scanB_kernel(int* __restrict__ bsums, int nb) {
    __shared__ int sh[128];
    int tid = threadIdx.x;
    int v = (tid < nb) ? bsums[tid] : 0;
    sh[tid] = v; __syncthreads();
    for (int off = 1; off < 128; off <<= 1) {
        int t = (tid >= off) ? sh[tid - off] : 0;
        __syncthreads();
        sh[tid] += t;
        __syncthreads();
    }
    if (tid < nb) bsums[tid] = sh[tid] - v;  // exclusive chunk offsets
}

__global__ void scanC_kernel(int* __restrict__ rowp, const int* __restrict__ bsums, int n) {
    int i = blockIdx.x * blockDim.x + threadIdx.x;
    if (i < n) {
        rowp[i + 1] += bsums[i >> 10];
        if (i == 0) rowp[0] = 0;
    }
}

// ---------------- pass B: bin edges into 256-node-range buckets, XCD-local ----------
// team = blockIdx&7 (XCD swizzle heuristic); team keeps buckets with (b&7)==team.
// Bucket base offsets come straight from rowp[b<<8]. Packs (d&255)<<24 | src (src<2^24).
__global__ __launch_bounds__(256) void binB_kernel(const int* __restrict__ src,
                                                   const int* __restrict__ dst,
                                                   const int* __restrict__ rowp,
                                                   int* __restrict__ bcursor,
                                                   unsigned int* __restrict__ binned,
                                                   int E) {
    int team = blockIdx.x & 7;
    int wb   = blockIdx.x >> 3;        // 64 blocks per team
    int chunk = (E + 63) >> 6;
    int e0 = wb * chunk;
    int e1 = min(e0 + chunk, E);
    for (int e = e0 + threadIdx.x; e < e1; e += 256) {
        int d = dst[e];
        int b = d >> 8;
        if ((b & 7) == team) {
            int base = rowp[d & ~255];          // rowp[b<<8], 391 hot entries in L2
            int pos = base + atomicAdd(&bcursor[b], 1);
            binned[pos] = ((unsigned int)(d & 255) << 24) | (unsigned int)src[e];
        }
    }
}

// ---------------- pass C: fine scatter within one bucket (one block per bucket) -----
__global__ __launch_bounds__(256) void binC_kernel(const unsigned int* __restrict__ binned,
                                                   const int* __restrict__ rowp,
                                                   int* __restrict__ csrc, int n) {
    __shared__ int rp[257];
    __shared__ int cur[256];
    int b = blockIdx.x;
    int nbase = b << 8;
    int nn = min(256, n - nbase);      // nodes in this bucket
    int tid = threadIdx.x;
    // load nn+1 row pointers (R8 fix: tid<=nn missed rp[256] when nn==256)
    for (int i = tid; i <= nn; i += 256) rp[i] = rowp[nbase + i];
    cur[tid] = 0;
    __syncthreads();
    int ebeg = rp[0], eend = rp[nn];
    for (int i = ebeg + tid; i < eend; i += 256) {
        unsigned int v = binned[i];
        int ld = v >> 24;
        int pos = rp[ld] + atomicAdd(&cur[ld], 1);
        csrc[pos] = (int)(v & 0xFFFFFFu);
    }
}

// ---------------- H = dinv ⊙ (X @ W)  (K=64, fp32 VALU) ----------------
// 64x64 tile per block; 256 threads as 16x16; each thread: 4 rows x 4 cols (16 acc).
// k-loop unroll capped at 2: full unroll hoists all 32 ds_read_b128 -> 256 VGPR
// (R4 evidence); unroll 2 keeps live set ~100 VGPR.
__global__ __launch_bounds__(256) void gemm64_kernel(const float* __restrict__ X,
                                                     const float* __restrict__ W,
                                                     const float* __restrict__ dscale,
                                                     float* __restrict__ H, int nrows) {
    __shared__ float Xs[64 * XS_STRIDE];
    __shared__ float Ws[64 * 64];
    int tid = threadIdx.x;
    int row0 = blockIdx.x * 64;

    {
        const float4* W4 = (const float4*)W;
#pragma unroll
        for (int i = 0; i < 4; i++) {
            int idx = tid + 256 * i;
            float4 v = W4[idx];
            int r = idx >> 4, kc = (idx & 15) << 2;
            *(float4*)&Ws[r * 64 + kc] = v;
        }
    }
    {
        const float4* X4 = (const float4*)(X + (size_t)row0 * NCH);
#pragma unroll
        for (int i = 0; i < 4; i++) {
            int idx = tid + 256 * i;
            int r = idx >> 4, kc = (idx & 15) << 2;
            if (row0 + r < nrows)
                *(float4*)&Xs[r * XS_STRIDE + kc] = X4[idx];
        }
    }
    __syncthreads();

    int c  = (tid & 15) << 2;
    int r0 = (tid >> 4) << 2;

    float4 acc[4];
#pragma unroll
    for (int i = 0; i < 4; i++) acc[i] = make_float4(0.f, 0.f, 0.f, 0.f);

#pragma unroll 2
    for (int k4 = 0; k4 < 16; k4++) {
        float4 wv[4], xv[4];
#pragma unroll
        for (int j = 0; j < 4; j++) wv[j] = *(const float4*)&Ws[(k4 * 4 + j) * 64 + c];
#pragma unroll
        for (int i = 0; i < 4; i++) xv[i] = *(const float4*)&Xs[(r0 + i) * XS_STRIDE + k4 * 4];
#pragma unroll
        for (int i = 0; i < 4; i++) {
            acc[i].x += xv[i].x * wv[0].x + xv[i].y * wv[1].x + xv[i].z * wv[2].x + xv[i].w * wv[3].x;
            acc[i].y += xv[i].x * wv[0].y + xv[i].y * wv[1].y + xv[i].z * wv[2].y + xv[i].w * wv[3].y;
            acc[i].z += xv[i].x * wv[0].z + xv[i].y * wv[1].z + xv[i].z * wv[2].z + xv[i].w * wv[3].z;
            acc[i].w += xv[i].x * wv[0].w + xv[i].y * wv[1].w + xv[i].z * wv[2].w + xv[i].w * wv[3].w;
        }
    }

#pragma unroll
    for (int i = 0; i < 4; i++) {
        int row = row0 + r0 + i;
        if (row < nrows) {
            float ds = dscale[row];
            acc[i].x *= ds; acc[i].y *= ds; acc[i].z *= ds; acc[i].w *= ds;
            *(float4*)&H[(size_t)row * NCH + c] = acc[i];
        }
    }
}

// ---------------- gather-aggregate: wave per node, lane per channel ----------------
// H pre-scaled by dinv[src]; out = b + dinv[node]*(H[node] + sum H[csrc[e]])
__global__ __launch_bounds__(256) void aggregate_kernel(const float* __restrict__ H,
                                                        const int* __restrict__ rowp,
                                                        const int* __restrict__ csrc,
                                                        const float* __restrict__ dinv,
                                                        const float* __restrict__ bias,
                                                        float* __restrict__ out,
                                                        int n, int do_relu) {
    int node = blockIdx.x * 4 + (threadIdx.x >> 6);
    int lane = threadIdx.x & 63;
    if (node >= n) return;
    float a0 = H[(size_t)node * NCH + lane];
    float a1 = 0.f, a2 = 0.f, a3 = 0.f;
    float a4 = 0.f, a5 = 0.f, a6 = 0.f, a7 = 0.f;
    int e = rowp[node];
    int end = rowp[node + 1];
    for (; e + 7 < end; e += 8) {
        int s0 = csrc[e];
        int s1 = csrc[e + 1];
        int s2 = csrc[e + 2];
        int s3 = csrc[e + 3];
        int s4 = csrc[e + 4];
        int s5 = csrc[e + 5];
        int s6 = csrc[e + 6];
        int s7 = csrc[e + 7];
        a0 += H[(size_t)s0 * NCH + lane];
        a1 += H[(size_t)s1 * NCH + lane];
        a2 += H[(size_t)s2 * NCH + lane];
        a3 += H[(size_t)s3 * NCH + lane];
        a4 += H[(size_t)s4 * NCH + lane];
        a5 += H[(size_t)s5 * NCH + lane];
        a6 += H[(size_t)s6 * NCH + lane];
        a7 += H[(size_t)s7 * NCH + lane];
    }
    if (e + 3 < end) {
        int s0 = csrc[e];
        int s1 = csrc[e + 1];
        int s2 = csrc[e + 2];
        int s3 = csrc[e + 3];
        a0 += H[(size_t)s0 * NCH + lane];
        a1 += H[(size_t)s1 * NCH + lane];
        a2 += H[(size_t)s2 * NCH + lane];
        a3 += H[(size_t)s3 * NCH + lane];
        e += 4;
    }
    for (; e < end; e++) {
        a0 += H[(size_t)csrc[e] * NCH + lane];
    }
    float sum = ((a0 + a1) + (a2 + a3)) + ((a4 + a5) + (a6 + a7));
    float acc = bias[lane] + dinv[node] * sum;
    if (do_relu) acc = fmaxf(acc, 0.f);
    out[(size_t)node * NCH + lane] = acc;
}

extern "C" void kernel_launch(void* const* d_in, const int* in_sizes, int n_in,
                              void* d_out, int out_size, void* d_ws, size_t ws_size,
                              hipStream_t stream) {
    const float* x  = (const float*)d_in[0];
    const int* edge = (const int*)d_in[1];
    const float* W1 = (const float*)d_in[2];
    const float* b1 = (const float*)d_in[3];
    const float* W2 = (const float*)d_in[4];
    const float* b2 = (const float*)d_in[5];
    float* out = (float*)d_out;

    const int N = in_sizes[0] / NCH;       // 100000
    const int E = in_sizes[1] / 2;         // 1200000
    const int* src = edge;
    const int* dst = edge + E;

    // workspace layout (16B-aligned blocks)
    char* w = (char*)d_ws;
    const size_t SZN = 400128;             // >= (N+1)*4, padded
    int*   counts  = (int*)(w + 0);
    int*   bcursor = (int*)(w + SZN);      // 391 bucket cursors (memset'd)
    int*   rowp    = (int*)(w + 2 * SZN);  // N+1 ints
    float* dinv    = (float*)(w + 3 * SZN);
    int*   bsums   = (int*)(w + 4 * SZN);  // 128 ints
    unsigned int* binned = (unsigned int*)(w + 4 * SZN + 512);        // E uints = 4.8 MB
    int*   csrc    = (int*)(w + 4 * SZN + 512 + (size_t)E * 4);       // E ints  = 4.8 MB
    float* h       = (float*)(w + 4 * SZN + 512 + (size_t)E * 8);     // N*64 floats

    const int NB_SCAN = (N + 1023) / 1024;  // 98
    const int NBUCK   = (N + 255) / 256;    // 391

    // 1) zero counts + bcursor
    hipMemsetAsync(counts, 0, 2 * SZN, stream);
    // 2) degree histogram over dst
    hist_kernel<<<(E + 255) / 256, 256, 0, stream>>>(dst, counts, E);
    // 3-5) exclusive scan counts -> rowp (dinv fused into scanA)
    scanA_kernel<<<NB_SCAN, 256, 0, stream>>>(counts, rowp, bsums, dinv, N);
    scanB_kernel<<<1, 128, 0, stream>>>(bsums, NB_SCAN);
    scanC_kernel<<<(N + 255) / 256, 256, 0, stream>>>(rowp, bsums, N);
    // 6) pass B: XCD-local bucket binning (512 blocks = 8 teams x 64)
    binB_kernel<<<512, 256, 0, stream>>>(src, dst, rowp, bcursor, binned, E);
    // 7) pass C: per-bucket fine scatter (LDS cursors)
    binC_kernel<<<NBUCK, 256, 0, stream>>>(binned, rowp, csrc, N);

    const int GB = (N + 63) / 64;      // gemm blocks (64 rows each)
    const int AB = (N + 3) / 4;        // aggregate blocks (4 waves/block)

    // Layer 1: h = dinv ⊙ (x@W1) ; d_out = relu(b1 + dinv ⊙ gather-sum(h))
    gemm64_kernel<<<GB, 256, 0, stream>>>(x, W1, dinv, h, N);
    aggregate_kernel<<<AB, 256, 0, stream>>>(h, rowp, csrc, dinv, b1, out, N, 1);
    // Layer 2: same with W2/b2, no relu
    gemm64_kernel<<<GB, 256, 0, stream>>>(out, W2, dinv, h, N);
    aggregate_kernel<<<AB, 256, 0, stream>>>(h, rowp, csrc, dinv, b2, out, N, 0);
}

// Round 9
// 265.625 us; speedup vs baseline: 4.3706x; 4.3706x over previous
//
#include <hip/hip_runtime.h>

// GCN 2-layer: per layer h = X@W; out[i] = b + dinv[i]^2*h[i] + sum_{e:dst=i} dinv[src]*dinv[i]*h[src]
// N=100000 nodes, E=1200000 edges, C=64 channels, fp32 throughout.
// Kept: dinv[src] folded into gemm epilogue; dinv[dst] applied once in aggregate;
//       csrc stores src only (4 B/edge); gather-aggregate wave/node.
// R9: atomic-free multisplit CSR build. R8 evidence: 1.2M global atomics on 391
//     bucket cursors = 866us pure serialization (plus cross-XCD cursor-line
//     ping-pong). Replace with: per-block LDS histograms -> bin-major table ->
//     3-phase scan (gives per-(bin,blk) bases AND bucket bases) -> ranked scatter
//     with LDS cursors -> per-bucket fine pass that also produces rowp/dinv/csrc.
//     Zero global atomics anywhere; no memset needed (every ws word is written).

#define NCH 64
#define XS_STRIDE 68   // 64 + 4 pad: keeps b128 16B alignment; 2-way conflicts only (free)
#define NBLK 256       // partition blocks; chunk = ceil(E/NBLK)
#define NBIN_MAX 512   // LDS array bound; runtime nbin = ceil(N/256) = 391

// ---------------- exclusive scan (3-phase), chunk = 1024 ----------------
// out[0]=0 (set in scanC), out[i+1] = inclusive sum through i.
__global__ __launch_bounds__(256) void scanA_kernel(const int* __restrict__ counts,
                                                    int* __restrict__ outp,
                                                    int* __restrict__ bsums, int n) {
    __shared__ int sh[256];
    int tid = threadIdx.x;
    int base = blockIdx.x * 1024;
    int v[4];
    int ts = 0;
#pragma unroll
    for (int j = 0; j < 4; j++) {
        int idx = base + tid * 4 + j;
        int c = (idx < n) ? counts[idx] : 0;
        v[j] = c; ts += c;
    }
    sh[tid] = ts; __syncthreads();
    for (int off = 1; off < 256; off <<= 1) {
        int t = (tid >= off) ? sh[tid - off] : 0;
        __syncthreads();
        sh[tid] += t;
        __syncthreads();
    }
    int run = sh[tid] - ts;
#pragma unroll
    for (int j = 0; j < 4; j++) {
        run += v[j];
        int idx = base + tid * 4 + j;
        if (idx < n) outp[idx + 1] = run;
    }
    if (tid == 255) bsums[blockIdx.x] = sh[255];
}

__global__ __launch_bounds__(128) void scanB_kernel(int* __restrict__ bsums, int nb) {
    __shared__ int sh[128];
    int tid = threadIdx.x;
    int v = (tid < nb) ? bsums[tid] : 0;
    sh[tid] = v; __syncthreads();
    for (int off = 1; off < 128; off <<= 1) {
        int t = (tid >= off) ? sh[tid - off] : 0;
        __syncthreads();
        sh[tid] += t;
        __syncthreads();
    }
    if (tid < nb) bsums[tid] = sh[tid] - v;
}

__global__ void scanC_kernel(int* __restrict__ outp, const int* __restrict__ bsums, int n) {
    int i = blockIdx.x * blockDim.x + threadIdx.x;
    if (i < n) {
        outp[i + 1] += bsums[i >> 10];
        if (i == 0) outp[0] = 0;
    }
}

// ---------------- phase 1: per-block bucket histogram (LDS only) ----------------
__global__ __launch_bounds__(256) void bhist_kernel(const int* __restrict__ dst,
                                                    int* __restrict__ table,
                                                    int E, int nbin) {
    __shared__ int hb[NBIN_MAX];
    int blk = blockIdx.x;
    for (int i = threadIdx.x; i < nbin; i += 256) hb[i] = 0;
    __syncthreads();
    int chunk = (E + NBLK - 1) / NBLK;
    int e0 = blk * chunk, e1 = min(e0 + chunk, E);
    for (int e = e0 + threadIdx.x; e < e1; e += 256)
        atomicAdd(&hb[dst[e] >> 8], 1);
    __syncthreads();
    for (int i = threadIdx.x; i < nbin; i += 256)
        table[i * NBLK + blk] = hb[i];   // bin-major: scan order = (bin, blk)
}

// ---------------- phase 3: ranked scatter into bucket-grouped 'binned' ----------
// base[(bin,blk)] = tscan[bin*NBLK+blk]; rank via LDS cursors; packs (d&255)<<24|src.
__global__ __launch_bounds__(256) void bscat_kernel(const int* __restrict__ src,
                                                    const int* __restrict__ dst,
                                                    const int* __restrict__ tscan,
                                                    unsigned int* __restrict__ binned,
                                                    int E, int nbin) {
    __shared__ int base[NBIN_MAX];
    __shared__ int cur[NBIN_MAX];
    int blk = blockIdx.x;
    for (int i = threadIdx.x; i < nbin; i += 256) {
        base[i] = tscan[i * NBLK + blk];
        cur[i] = 0;
    }
    __syncthreads();
    int chunk = (E + NBLK - 1) / NBLK;
    int e0 = blk * chunk, e1 = min(e0 + chunk, E);
    for (int e = e0 + threadIdx.x; e < e1; e += 256) {
        int d = dst[e];
        int b = d >> 8;
        int r = atomicAdd(&cur[b], 1);   // LDS atomic, ~12 hits/address
        binned[base[b] + r] = ((unsigned int)(d & 255) << 24) | (unsigned int)src[e];
    }
}

// ---------------- phase 4: per-bucket fine pass -> rowp, dinv, csrc ----------------
// Bucket b region in binned = [tscan[b*NBLK], tscan[(b+1)*NBLK]) (tscan[NT]=E).
__global__ __launch_bounds__(256) void bfine_kernel(const unsigned int* __restrict__ binned,
                                                    const int* __restrict__ tscan,
                                                    int* __restrict__ rowp,
                                                    float* __restrict__ dinv,
                                                    int* __restrict__ csrc,
                                                    int N, int nbin) {
    __shared__ int deg[256];
    __shared__ int sc[256];
    __shared__ int nodebase[256];
    int b = blockIdx.x;
    int nbase = b << 8;
    int nn = min(256, N - nbase);
    int tid = threadIdx.x;
    int bucket_base = tscan[b * NBLK];
    int bucket_end  = tscan[(b + 1) * NBLK];

    deg[tid] = 0;
    __syncthreads();
    for (int i = bucket_base + tid; i < bucket_end; i += 256)
        atomicAdd(&deg[binned[i] >> 24], 1);
    __syncthreads();
    int v = deg[tid];
    sc[tid] = v;
    __syncthreads();
    for (int off = 1; off < 256; off <<= 1) {
        int t = (tid >= off) ? sc[tid - off] : 0;
        __syncthreads();
        sc[tid] += t;
        __syncthreads();
    }
    int excl = sc[tid] - v;
    nodebase[tid] = bucket_base + excl;
    if (tid < nn) {
        rowp[nbase + tid] = bucket_base + excl;
        dinv[nbase + tid] = rsqrtf((float)(v + 1));  // +1 self loop
    }
    if (nbase + nn == N && tid == 255) rowp[N] = bucket_base + sc[255];
    deg[tid] = 0;                       // reuse as cursor
    __syncthreads();
    for (int i = bucket_base + tid; i < bucket_end; i += 256) {
        unsigned int u = binned[i];
        int ld = u >> 24;
        int pos = nodebase[ld] + atomicAdd(&deg[ld], 1);
        csrc[pos] = (int)(u & 0xFFFFFFu);
    }
}

// ---------------- H = dinv ⊙ (X @ W)  (K=64, fp32 VALU) ----------------
// 64x64 tile per block; 256 threads as 16x16; each thread: 4 rows x 4 cols (16 acc).
// k-loop unroll capped at 2 (R4: full unroll -> 256 VGPR; R3: forced cap -> spills).
__global__ __launch_bounds__(256) void gemm64_kernel(const float* __restrict__ X,
                                                     const float* __restrict__ W,
                                                     const float* __restrict__ dscale,
                                                     float* __restrict__ H, int nrows) {
    __shared__ float Xs[64 * XS_STRIDE];
    __shared__ float Ws[64 * 64];
    int tid = threadIdx.x;
    int row0 = blockIdx.x * 64;

    {
        const float4* W4 = (const float4*)W;
#pragma unroll
        for (int i = 0; i < 4; i++) {
            int idx = tid + 256 * i;
            float4 v = W4[idx];
            int r = idx >> 4, kc = (idx & 15) << 2;
            *(float4*)&Ws[r * 64 + kc] = v;
        }
    }
    {
        const float4* X4 = (const float4*)(X + (size_t)row0 * NCH);
#pragma unroll
        for (int i = 0; i < 4; i++) {
            int idx = tid + 256 * i;
            int r = idx >> 4, kc = (idx & 15) << 2;
            if (row0 + r < nrows)
                *(float4*)&Xs[r * XS_STRIDE + kc] = X4[idx];
        }
    }
    __syncthreads();

    int c  = (tid & 15) << 2;
    int r0 = (tid >> 4) << 2;

    float4 acc[4];
#pragma unroll
    for (int i = 0; i < 4; i++) acc[i] = make_float4(0.f, 0.f, 0.f, 0.f);

#pragma unroll 2
    for (int k4 = 0; k4 < 16; k4++) {
        float4 wv[4], xv[4];
#pragma unroll
        for (int j = 0; j < 4; j++) wv[j] = *(const float4*)&Ws[(k4 * 4 + j) * 64 + c];
#pragma unroll
        for (int i = 0; i < 4; i++) xv[i] = *(const float4*)&Xs[(r0 + i) * XS_STRIDE + k4 * 4];
#pragma unroll
        for (int i = 0; i < 4; i++) {
            acc[i].x += xv[i].x * wv[0].x + xv[i].y * wv[1].x + xv[i].z * wv[2].x + xv[i].w * wv[3].x;
            acc[i].y += xv[i].x * wv[0].y + xv[i].y * wv[1].y + xv[i].z * wv[2].y + xv[i].w * wv[3].y;
            acc[i].z += xv[i].x * wv[0].z + xv[i].y * wv[1].z + xv[i].z * wv[2].z + xv[i].w * wv[3].z;
            acc[i].w += xv[i].x * wv[0].w + xv[i].y * wv[1].w + xv[i].z * wv[2].w + xv[i].w * wv[3].w;
        }
    }

#pragma unroll
    for (int i = 0; i < 4; i++) {
        int row = row0 + r0 + i;
        if (row < nrows) {
            float ds = dscale[row];
            acc[i].x *= ds; acc[i].y *= ds; acc[i].z *= ds; acc[i].w *= ds;
            *(float4*)&H[(size_t)row * NCH + c] = acc[i];
        }
    }
}

// ---------------- gather-aggregate: wave per node, lane per channel ----------------
// H pre-scaled by dinv[src]; out = b + dinv[node]*(H[node] + sum H[csrc[e]])
__global__ __launch_bounds__(256) void aggregate_kernel(const float* __restrict__ H,
                                                        const int* __restrict__ rowp,
                                                        const int* __restrict__ csrc,
                                                        const float* __restrict__ dinv,
                                                        const float* __restrict__ bias,
                                                        float* __restrict__ out,
                                                        int n, int do_relu) {
    int node = blockIdx.x * 4 + (threadIdx.x >> 6);
    int lane = threadIdx.x & 63;
    if (node >= n) return;
    float a0 = H[(size_t)node * NCH + lane];
    float a1 = 0.f, a2 = 0.f, a3 = 0.f;
    float a4 = 0.f, a5 = 0.f, a6 = 0.f, a7 = 0.f;
    int e = rowp[node];
    int end = rowp[node + 1];
    for (; e + 7 < end; e += 8) {
        int s0 = csrc[e];
        int s1 = csrc[e + 1];
        int s2 = csrc[e + 2];
        int s3 = csrc[e + 3];
        int s4 = csrc[e + 4];
        int s5 = csrc[e + 5];
        int s6 = csrc[e + 6];
        int s7 = csrc[e + 7];
        a0 += H[(size_t)s0 * NCH + lane];
        a1 += H[(size_t)s1 * NCH + lane];
        a2 += H[(size_t)s2 * NCH + lane];
        a3 += H[(size_t)s3 * NCH + lane];
        a4 += H[(size_t)s4 * NCH + lane];
        a5 += H[(size_t)s5 * NCH + lane];
        a6 += H[(size_t)s6 * NCH + lane];
        a7 += H[(size_t)s7 * NCH + lane];
    }
    if (e + 3 < end) {
        int s0 = csrc[e];
        int s1 = csrc[e + 1];
        int s2 = csrc[e + 2];
        int s3 = csrc[e + 3];
        a0 += H[(size_t)s0 * NCH + lane];
        a1 += H[(size_t)s1 * NCH + lane];
        a2 += H[(size_t)s2 * NCH + lane];
        a3 += H[(size_t)s3 * NCH + lane];
        e += 4;
    }
    for (; e < end; e++) {
        a0 += H[(size_t)csrc[e] * NCH + lane];
    }
    float sum = ((a0 + a1) + (a2 + a3)) + ((a4 + a5) + (a6 + a7));
    float acc = bias[lane] + dinv[node] * sum;
    if (do_relu) acc = fmaxf(acc, 0.f);
    out[(size_t)node * NCH + lane] = acc;
}

extern "C" void kernel_launch(void* const* d_in, const int* in_sizes, int n_in,
                              void* d_out, int out_size, void* d_ws, size_t ws_size,
                              hipStream_t stream) {
    const float* x  = (const float*)d_in[0];
    const int* edge = (const int*)d_in[1];
    const float* W1 = (const float*)d_in[2];
    const float* b1 = (const float*)d_in[3];
    const float* W2 = (const float*)d_in[4];
    const float* b2 = (const float*)d_in[5];
    float* out = (float*)d_out;

    const int N = in_sizes[0] / NCH;       // 100000
    const int E = in_sizes[1] / 2;         // 1200000
    const int* src = edge;
    const int* dst = edge + E;

    const int nbin = (N + 255) >> 8;       // 391
    const int NT   = nbin * NBLK;          // 100096 table entries

    // workspace layout (16B-aligned blocks); every byte used is written each call.
    char* w = (char*)d_ws;
    const size_t SZT = 401408;             // >= (NT+1)*4
    const size_t SZN = 400896;             // >= (N+1)*4
    int*   table  = (int*)(w + 0);                 // NT ints
    int*   tscan  = (int*)(w + SZT);               // NT+1 ints
    int*   rowp   = (int*)(w + 2 * SZT);           // N+1 ints
    float* dinv   = (float*)(w + 2 * SZT + SZN);   // N floats
    int*   bsums  = (int*)(w + 2 * SZT + 2 * SZN); // 128 ints
    unsigned int* binned = (unsigned int*)(w + 2 * SZT + 2 * SZN + 512);   // E uints
    int*   csrc   = (int*)(w + 2 * SZT + 2 * SZN + 512 + (size_t)E * 4);   // E ints
    float* h      = (float*)(w + 2 * SZT + 2 * SZN + 512 + (size_t)E * 8); // N*64 floats

    const int NB_SCAN_T = (NT + 1023) / 1024;   // 98

    // CSR build (atomic-free at global scope)
    bhist_kernel<<<NBLK, 256, 0, stream>>>(dst, table, E, nbin);
    scanA_kernel<<<NB_SCAN_T, 256, 0, stream>>>(table, tscan, bsums, NT);
    scanB_kernel<<<1, 128, 0, stream>>>(bsums, NB_SCAN_T);
    scanC_kernel<<<(NT + 255) / 256, 256, 0, stream>>>(tscan, bsums, NT);
    bscat_kernel<<<NBLK, 256, 0, stream>>>(src, dst, tscan, binned, E, nbin);
    bfine_kernel<<<nbin, 256, 0, stream>>>(binned, tscan, rowp, dinv, csrc, N, nbin);

    const int GB = (N + 63) / 64;      // gemm blocks (64 rows each)
    const int AB = (N + 3) / 4;        // aggregate blocks (4 waves/block)

    // Layer 1: h = dinv ⊙ (x@W1) ; d_out = relu(b1 + dinv ⊙ gather-sum(h))
    gemm64_kernel<<<GB, 256, 0, stream>>>(x, W1, dinv, h, N);
    aggregate_kernel<<<AB, 256, 0, stream>>>(h, rowp, csrc, dinv, b1, out, N, 1);
    // Layer 2: same with W2/b2, no relu
    gemm64_kernel<<<GB, 256, 0, stream>>>(out, W2, dinv, h, N);
    aggregate_kernel<<<AB, 256, 0, stream>>>(h, rowp, csrc, dinv, b2, out, N, 0);
}

// Round 10
// 254.968 us; speedup vs baseline: 4.5533x; 1.0418x over previous
//
#include <hip/hip_runtime.h>

// GCN 2-layer: per layer h = X@W; out[i] = b + dinv[i]^2*h[i] + sum_{e:dst=i} dinv[src]*dinv[i]*h[src]
// N=100000 nodes, E=1200000 edges, C=64 channels.
// Kept: dinv[src] folded into gemm epilogue; dinv[dst] applied once in aggregate;
//       atomic-free multisplit CSR build (R9: 866us atomics -> ~40us);
//       gather-aggregate wave/node with depth-8 MLP.
// R10: H stored as bf16. R9 evidence: aggregate is gather-BW-bound (147 MB
//      fabric fetch/dispatch = random 256 B rows from 25.6 MB H, ~half L2-missed).
//      bf16 halves row size -> 128 B/gather. GEMM inputs (x, layer-1 activation)
//      and final output stay fp32; only the post-GEMM H is bf16 (RNE).

#define NCH 64
#define XS_STRIDE 68   // 64 + 4 pad: keeps b128 16B alignment; 2-way conflicts only (free)
#define NBLK 256       // partition blocks; chunk = ceil(E/NBLK)
#define NBIN_MAX 512   // LDS array bound; runtime nbin = ceil(N/256) = 391

static __device__ __forceinline__ unsigned short f2bf(float f) {
    unsigned int u = __float_as_uint(f);
    unsigned int r = (u + 0x7FFFu + ((u >> 16) & 1u)) >> 16;  // round-to-nearest-even
    return (unsigned short)r;
}
static __device__ __forceinline__ float bf2f(unsigned short h) {
    return __uint_as_float(((unsigned int)h) << 16);
}

// ---------------- exclusive scan (3-phase), chunk = 1024 ----------------
__global__ __launch_bounds__(256) void scanA_kernel(const int* __restrict__ counts,
                                                    int* __restrict__ outp,
                                                    int* __restrict__ bsums, int n) {
    __shared__ int sh[256];
    int tid = threadIdx.x;
    int base = blockIdx.x * 1024;
    int v[4];
    int ts = 0;
#pragma unroll
    for (int j = 0; j < 4; j++) {
        int idx = base + tid * 4 + j;
        int c = (idx < n) ? counts[idx] : 0;
        v[j] = c; ts += c;
    }
    sh[tid] = ts; __syncthreads();
    for (int off = 1; off < 256; off <<= 1) {
        int t = (tid >= off) ? sh[tid - off] : 0;
        __syncthreads();
        sh[tid] += t;
        __syncthreads();
    }
    int run = sh[tid] - ts;
#pragma unroll
    for (int j = 0; j < 4; j++) {
        run += v[j];
        int idx = base + tid * 4 + j;
        if (idx < n) outp[idx + 1] = run;
    }
    if (tid == 255) bsums[blockIdx.x] = sh[255];
}

__global__ __launch_bounds__(128) void scanB_kernel(int* __restrict__ bsums, int nb) {
    __shared__ int sh[128];
    int tid = threadIdx.x;
    int v = (tid < nb) ? bsums[tid] : 0;
    sh[tid] = v; __syncthreads();
    for (int off = 1; off < 128; off <<= 1) {
        int t = (tid >= off) ? sh[tid - off] : 0;
        __syncthreads();
        sh[tid] += t;
        __syncthreads();
    }
    if (tid < nb) bsums[tid] = sh[tid] - v;
}

__global__ void scanC_kernel(int* __restrict__ outp, const int* __restrict__ bsums, int n) {
    int i = blockIdx.x * blockDim.x + threadIdx.x;
    if (i < n) {
        outp[i + 1] += bsums[i >> 10];
        if (i == 0) outp[0] = 0;
    }
}

// ---------------- phase 1: per-block bucket histogram (LDS only) ----------------
__global__ __launch_bounds__(256) void bhist_kernel(const int* __restrict__ dst,
                                                    int* __restrict__ table,
                                                    int E, int nbin) {
    __shared__ int hb[NBIN_MAX];
    int blk = blockIdx.x;
    for (int i = threadIdx.x; i < nbin; i += 256) hb[i] = 0;
    __syncthreads();
    int chunk = (E + NBLK - 1) / NBLK;
    int e0 = blk * chunk, e1 = min(e0 + chunk, E);
    for (int e = e0 + threadIdx.x; e < e1; e += 256)
        atomicAdd(&hb[dst[e] >> 8], 1);
    __syncthreads();
    for (int i = threadIdx.x; i < nbin; i += 256)
        table[i * NBLK + blk] = hb[i];   // bin-major: scan order = (bin, blk)
}

// ---------------- phase 3: ranked scatter into bucket-grouped 'binned' ----------
__global__ __launch_bounds__(256) void bscat_kernel(const int* __restrict__ src,
                                                    const int* __restrict__ dst,
                                                    const int* __restrict__ tscan,
                                                    unsigned int* __restrict__ binned,
                                                    int E, int nbin) {
    __shared__ int base[NBIN_MAX];
    __shared__ int cur[NBIN_MAX];
    int blk = blockIdx.x;
    for (int i = threadIdx.x; i < nbin; i += 256) {
        base[i] = tscan[i * NBLK + blk];
        cur[i] = 0;
    }
    __syncthreads();
    int chunk = (E + NBLK - 1) / NBLK;
    int e0 = blk * chunk, e1 = min(e0 + chunk, E);
    for (int e = e0 + threadIdx.x; e < e1; e += 256) {
        int d = dst[e];
        int b = d >> 8;
        int r = atomicAdd(&cur[b], 1);   // LDS atomic, ~12 hits/address
        binned[base[b] + r] = ((unsigned int)(d & 255) << 24) | (unsigned int)src[e];
    }
}

// ---------------- phase 4: per-bucket fine pass -> rowp, dinv, csrc ----------------
__global__ __launch_bounds__(256) void bfine_kernel(const unsigned int* __restrict__ binned,
                                                    const int* __restrict__ tscan,
                                                    int* __restrict__ rowp,
                                                    float* __restrict__ dinv,
                                                    int* __restrict__ csrc,
                                                    int N, int nbin) {
    __shared__ int deg[256];
    __shared__ int sc[256];
    __shared__ int nodebase[256];
    int b = blockIdx.x;
    int nbase = b << 8;
    int nn = min(256, N - nbase);
    int tid = threadIdx.x;
    int bucket_base = tscan[b * NBLK];
    int bucket_end  = tscan[(b + 1) * NBLK];

    deg[tid] = 0;
    __syncthreads();
    for (int i = bucket_base + tid; i < bucket_end; i += 256)
        atomicAdd(&deg[binned[i] >> 24], 1);
    __syncthreads();
    int v = deg[tid];
    sc[tid] = v;
    __syncthreads();
    for (int off = 1; off < 256; off <<= 1) {
        int t = (tid >= off) ? sc[tid - off] : 0;
        __syncthreads();
        sc[tid] += t;
        __syncthreads();
    }
    int excl = sc[tid] - v;
    nodebase[tid] = bucket_base + excl;
    if (tid < nn) {
        rowp[nbase + tid] = bucket_base + excl;
        dinv[nbase + tid] = rsqrtf((float)(v + 1));  // +1 self loop
    }
    if (nbase + nn == N && tid == 255) rowp[N] = bucket_base + sc[255];
    deg[tid] = 0;                       // reuse as cursor
    __syncthreads();
    for (int i = bucket_base + tid; i < bucket_end; i += 256) {
        unsigned int u = binned[i];
        int ld = u >> 24;
        int pos = nodebase[ld] + atomicAdd(&deg[ld], 1);
        csrc[pos] = (int)(u & 0xFFFFFFu);
    }
}

// ---------------- H(bf16) = dinv ⊙ (X @ W)  (K=64, fp32 VALU) ----------------
// 64x64 tile per block; 256 threads as 16x16; each thread: 4 rows x 4 cols (16 acc).
// k-loop unroll capped at 2 (R4: full unroll -> 256 VGPR; R3: forced cap -> spills).
__global__ __launch_bounds__(256) void gemm64_kernel(const float* __restrict__ X,
                                                     const float* __restrict__ W,
                                                     const float* __restrict__ dscale,
                                                     unsigned short* __restrict__ H,
                                                     int nrows) {
    __shared__ float Xs[64 * XS_STRIDE];
    __shared__ float Ws[64 * 64];
    int tid = threadIdx.x;
    int row0 = blockIdx.x * 64;

    {
        const float4* W4 = (const float4*)W;
#pragma unroll
        for (int i = 0; i < 4; i++) {
            int idx = tid + 256 * i;
            float4 v = W4[idx];
            int r = idx >> 4, kc = (idx & 15) << 2;
            *(float4*)&Ws[r * 64 + kc] = v;
        }
    }
    {
        const float4* X4 = (const float4*)(X + (size_t)row0 * NCH);
#pragma unroll
        for (int i = 0; i < 4; i++) {
            int idx = tid + 256 * i;
            int r = idx >> 4, kc = (idx & 15) << 2;
            if (row0 + r < nrows)
                *(float4*)&Xs[r * XS_STRIDE + kc] = X4[idx];
        }
    }
    __syncthreads();

    int c  = (tid & 15) << 2;
    int r0 = (tid >> 4) << 2;

    float4 acc[4];
#pragma unroll
    for (int i = 0; i < 4; i++) acc[i] = make_float4(0.f, 0.f, 0.f, 0.f);

#pragma unroll 2
    for (int k4 = 0; k4 < 16; k4++) {
        float4 wv[4], xv[4];
#pragma unroll
        for (int j = 0; j < 4; j++) wv[j] = *(const float4*)&Ws[(k4 * 4 + j) * 64 + c];
#pragma unroll
        for (int i = 0; i < 4; i++) xv[i] = *(const float4*)&Xs[(r0 + i) * XS_STRIDE + k4 * 4];
#pragma unroll
        for (int i = 0; i < 4; i++) {
            acc[i].x += xv[i].x * wv[0].x + xv[i].y * wv[1].x + xv[i].z * wv[2].x + xv[i].w * wv[3].x;
            acc[i].y += xv[i].x * wv[0].y + xv[i].y * wv[1].y + xv[i].z * wv[2].y + xv[i].w * wv[3].y;
            acc[i].z += xv[i].x * wv[0].z + xv[i].y * wv[1].z + xv[i].z * wv[2].z + xv[i].w * wv[3].z;
            acc[i].w += xv[i].x * wv[0].w + xv[i].y * wv[1].w + xv[i].z * wv[2].w + xv[i].w * wv[3].w;
        }
    }

#pragma unroll
    for (int i = 0; i < 4; i++) {
        int row = row0 + r0 + i;
        if (row < nrows) {
            float ds = dscale[row];
            ushort4 o;
            o.x = f2bf(acc[i].x * ds);
            o.y = f2bf(acc[i].y * ds);
            o.z = f2bf(acc[i].z * ds);
            o.w = f2bf(acc[i].w * ds);
            *(ushort4*)&H[(size_t)row * NCH + c] = o;   // 8 B aligned (c%4==0)
        }
    }
}

// ---------------- gather-aggregate: wave per node, lane per channel ----------------
// H bf16, pre-scaled by dinv[src]; out = b + dinv[node]*(H[node] + sum H[csrc[e]])
__global__ __launch_bounds__(256) void aggregate_kernel(const unsigned short* __restrict__ H,
                                                        const int* __restrict__ rowp,
                                                        const int* __restrict__ csrc,
                                                        const float* __restrict__ dinv,
                                                        const float* __restrict__ bias,
                                                        float* __restrict__ out,
                                                        int n, int do_relu) {
    int node = blockIdx.x * 4 + (threadIdx.x >> 6);
    int lane = threadIdx.x & 63;
    if (node >= n) return;
    float a0 = bf2f(H[(size_t)node * NCH + lane]);
    float a1 = 0.f, a2 = 0.f, a3 = 0.f;
    float a4 = 0.f, a5 = 0.f, a6 = 0.f, a7 = 0.f;
    int e = rowp[node];
    int end = rowp[node + 1];
    for (; e + 7 < end; e += 8) {
        int s0 = csrc[e];
        int s1 = csrc[e + 1];
        int s2 = csrc[e + 2];
        int s3 = csrc[e + 3];
        int s4 = csrc[e + 4];
        int s5 = csrc[e + 5];
        int s6 = csrc[e + 6];
        int s7 = csrc[e + 7];
        unsigned short h0 = H[(size_t)s0 * NCH + lane];
        unsigned short h1 = H[(size_t)s1 * NCH + lane];
        unsigned short h2 = H[(size_t)s2 * NCH + lane];
        unsigned short h3 = H[(size_t)s3 * NCH + lane];
        unsigned short h4 = H[(size_t)s4 * NCH + lane];
        unsigned short h5 = H[(size_t)s5 * NCH + lane];
        unsigned short h6 = H[(size_t)s6 * NCH + lane];
        unsigned short h7 = H[(size_t)s7 * NCH + lane];
        a0 += bf2f(h0);
        a1 += bf2f(h1);
        a2 += bf2f(h2);
        a3 += bf2f(h3);
        a4 += bf2f(h4);
        a5 += bf2f(h5);
        a6 += bf2f(h6);
        a7 += bf2f(h7);
    }
    if (e + 3 < end) {
        int s0 = csrc[e];
        int s1 = csrc[e + 1];
        int s2 = csrc[e + 2];
        int s3 = csrc[e + 3];
        unsigned short h0 = H[(size_t)s0 * NCH + lane];
        unsigned short h1 = H[(size_t)s1 * NCH + lane];
        unsigned short h2 = H[(size_t)s2 * NCH + lane];
        unsigned short h3 = H[(size_t)s3 * NCH + lane];
        a0 += bf2f(h0);
        a1 += bf2f(h1);
        a2 += bf2f(h2);
        a3 += bf2f(h3);
        e += 4;
    }
    for (; e < end; e++) {
        a0 += bf2f(H[(size_t)csrc[e] * NCH + lane]);
    }
    float sum = ((a0 + a1) + (a2 + a3)) + ((a4 + a5) + (a6 + a7));
    float acc = bias[lane] + dinv[node] * sum;
    if (do_relu) acc = fmaxf(acc, 0.f);
    out[(size_t)node * NCH + lane] = acc;
}

extern "C" void kernel_launch(void* const* d_in, const int* in_sizes, int n_in,
                              void* d_out, int out_size, void* d_ws, size_t ws_size,
                              hipStream_t stream) {
    const float* x  = (const float*)d_in[0];
    const int* edge = (const int*)d_in[1];
    const float* W1 = (const float*)d_in[2];
    const float* b1 = (const float*)d_in[3];
    const float* W2 = (const float*)d_in[4];
    const float* b2 = (const float*)d_in[5];
    float* out = (float*)d_out;

    const int N = in_sizes[0] / NCH;       // 100000
    const int E = in_sizes[1] / 2;         // 1200000
    const int* src = edge;
    const int* dst = edge + E;

    const int nbin = (N + 255) >> 8;       // 391
    const int NT   = nbin * NBLK;          // 100096 table entries

    // workspace layout (16B-aligned blocks); every word used is written each call.
    char* w = (char*)d_ws;
    const size_t SZT = 401408;             // >= (NT+1)*4
    const size_t SZN = 400896;             // >= (N+1)*4
    int*   table  = (int*)(w + 0);                 // NT ints
    int*   tscan  = (int*)(w + SZT);               // NT+1 ints
    int*   rowp   = (int*)(w + 2 * SZT);           // N+1 ints
    float* dinv   = (float*)(w + 2 * SZT + SZN);   // N floats
    int*   bsums  = (int*)(w + 2 * SZT + 2 * SZN); // 128 ints
    unsigned int* binned = (unsigned int*)(w + 2 * SZT + 2 * SZN + 512);   // E uints
    int*   csrc   = (int*)(w + 2 * SZT + 2 * SZN + 512 + (size_t)E * 4);   // E ints
    unsigned short* h = (unsigned short*)(w + 2 * SZT + 2 * SZN + 512 + (size_t)E * 8); // N*64 bf16

    const int NB_SCAN_T = (NT + 1023) / 1024;   // 98

    // CSR build (atomic-free at global scope)
    bhist_kernel<<<NBLK, 256, 0, stream>>>(dst, table, E, nbin);
    scanA_kernel<<<NB_SCAN_T, 256, 0, stream>>>(table, tscan, bsums, NT);
    scanB_kernel<<<1, 128, 0, stream>>>(bsums, NB_SCAN_T);
    scanC_kernel<<<(NT + 255) / 256, 256, 0, stream>>>(tscan, bsums, NT);
    bscat_kernel<<<NBLK, 256, 0, stream>>>(src, dst, tscan, binned, E, nbin);
    bfine_kernel<<<nbin, 256, 0, stream>>>(binned, tscan, rowp, dinv, csrc, N, nbin);

    const int GB = (N + 63) / 64;      // gemm blocks (64 rows each)
    const int AB = (N + 3) / 4;        // aggregate blocks (4 waves/block)

    // Layer 1: h = bf16(dinv ⊙ (x@W1)) ; d_out = relu(b1 + dinv ⊙ gather-sum(h))
    gemm64_kernel<<<GB, 256, 0, stream>>>(x, W1, dinv, h, N);
    aggregate_kernel<<<AB, 256, 0, stream>>>(h, rowp, csrc, dinv, b1, out, N, 1);
    // Layer 2: same with W2/b2, no relu
    gemm64_kernel<<<GB, 256, 0, stream>>>(out, W2, dinv, h, N);
    aggregate_kernel<<<AB, 256, 0, stream>>>(h, rowp, csrc, dinv, b2, out, N, 0);
}

// Round 11
// 253.768 us; speedup vs baseline: 4.5748x; 1.0047x over previous
//
#include <hip/hip_runtime.h>

// GCN 2-layer: per layer h = X@W; out[i] = b + dinv[i]^2*h[i] + sum_{e:dst=i} dinv[src]*dinv[i]*h[src]
// N=100000 nodes, E=1200000 edges, C=64 channels.
// Kept: dinv[src] folded into gemm epilogue; dinv[dst] applied once in aggregate;
//       atomic-free multisplit CSR build (R9); bf16 H (R10: halved gather fetch).
// R11: aggregate processes 2 edges/wave-instruction — lane covers a channel PAIR
//      (ushort2, 4 B), half-wave 0 = edge i, half-wave 1 = edge i+1; cross-half
//      shfl_xor(32) reduce. R10 evidence: fetch halved but dur only -10% ->
//      issue/latency-bound at 2 B/lane; 4 B/lane halves per-edge VALU + trips.
//      Also: layer-1 activation stored bf16 (ws), gemm2 stages bf16->LDS fp32.

#define NCH 64
#define XS_STRIDE 68   // 64 + 4 pad: keeps b128 16B alignment; 2-way conflicts only (free)
#define NBLK 256       // partition blocks; chunk = ceil(E/NBLK)
#define NBIN_MAX 512   // LDS array bound; runtime nbin = ceil(N/256) = 391

static __device__ __forceinline__ unsigned short f2bf(float f) {
    unsigned int u = __float_as_uint(f);
    unsigned int r = (u + 0x7FFFu + ((u >> 16) & 1u)) >> 16;  // round-to-nearest-even
    return (unsigned short)r;
}
static __device__ __forceinline__ float bf2f(unsigned short h) {
    return __uint_as_float(((unsigned int)h) << 16);
}

// ---------------- exclusive scan (3-phase), chunk = 1024 ----------------
__global__ __launch_bounds__(256) void scanA_kernel(const int* __restrict__ counts,
                                                    int* __restrict__ outp,
                                                    int* __restrict__ bsums, int n) {
    __shared__ int sh[256];
    int tid = threadIdx.x;
    int base = blockIdx.x * 1024;
    int v[4];
    int ts = 0;
#pragma unroll
    for (int j = 0; j < 4; j++) {
        int idx = base + tid * 4 + j;
        int c = (idx < n) ? counts[idx] : 0;
        v[j] = c; ts += c;
    }
    sh[tid] = ts; __syncthreads();
    for (int off = 1; off < 256; off <<= 1) {
        int t = (tid >= off) ? sh[tid - off] : 0;
        __syncthreads();
        sh[tid] += t;
        __syncthreads();
    }
    int run = sh[tid] - ts;
#pragma unroll
    for (int j = 0; j < 4; j++) {
        run += v[j];
        int idx = base + tid * 4 + j;
        if (idx < n) outp[idx + 1] = run;
    }
    if (tid == 255) bsums[blockIdx.x] = sh[255];
}

__global__ __launch_bounds__(128) void scanB_kernel(int* __restrict__ bsums, int nb) {
    __shared__ int sh[128];
    int tid = threadIdx.x;
    int v = (tid < nb) ? bsums[tid] : 0;
    sh[tid] = v; __syncthreads();
    for (int off = 1; off < 128; off <<= 1) {
        int t = (tid >= off) ? sh[tid - off] : 0;
        __syncthreads();
        sh[tid] += t;
        __syncthreads();
    }
    if (tid < nb) bsums[tid] = sh[tid] - v;
}

__global__ void scanC_kernel(int* __restrict__ outp, const int* __restrict__ bsums, int n) {
    int i = blockIdx.x * blockDim.x + threadIdx.x;
    if (i < n) {
        outp[i + 1] += bsums[i >> 10];
        if (i == 0) outp[0] = 0;
    }
}

// ---------------- phase 1: per-block bucket histogram (LDS only) ----------------
__global__ __launch_bounds__(256) void bhist_kernel(const int* __restrict__ dst,
                                                    int* __restrict__ table,
                                                    int E, int nbin) {
    __shared__ int hb[NBIN_MAX];
    int blk = blockIdx.x;
    for (int i = threadIdx.x; i < nbin; i += 256) hb[i] = 0;
    __syncthreads();
    int chunk = (E + NBLK - 1) / NBLK;
    int e0 = blk * chunk, e1 = min(e0 + chunk, E);
    for (int e = e0 + threadIdx.x; e < e1; e += 256)
        atomicAdd(&hb[dst[e] >> 8], 1);
    __syncthreads();
    for (int i = threadIdx.x; i < nbin; i += 256)
        table[i * NBLK + blk] = hb[i];   // bin-major: scan order = (bin, blk)
}

// ---------------- phase 3: ranked scatter into bucket-grouped 'binned' ----------
__global__ __launch_bounds__(256) void bscat_kernel(const int* __restrict__ src,
                                                    const int* __restrict__ dst,
                                                    const int* __restrict__ tscan,
                                                    unsigned int* __restrict__ binned,
                                                    int E, int nbin) {
    __shared__ int base[NBIN_MAX];
    __shared__ int cur[NBIN_MAX];
    int blk = blockIdx.x;
    for (int i = threadIdx.x; i < nbin; i += 256) {
        base[i] = tscan[i * NBLK + blk];
        cur[i] = 0;
    }
    __syncthreads();
    int chunk = (E + NBLK - 1) / NBLK;
    int e0 = blk * chunk, e1 = min(e0 + chunk, E);
    for (int e = e0 + threadIdx.x; e < e1; e += 256) {
        int d = dst[e];
        int b = d >> 8;
        int r = atomicAdd(&cur[b], 1);   // LDS atomic, ~12 hits/address
        binned[base[b] + r] = ((unsigned int)(d & 255) << 24) | (unsigned int)src[e];
    }
}

// ---------------- phase 4: per-bucket fine pass -> rowp, dinv, csrc ----------------
__global__ __launch_bounds__(256) void bfine_kernel(const unsigned int* __restrict__ binned,
                                                    const int* __restrict__ tscan,
                                                    int* __restrict__ rowp,
                                                    float* __restrict__ dinv,
                                                    int* __restrict__ csrc,
                                                    int N, int nbin) {
    __shared__ int deg[256];
    __shared__ int sc[256];
    __shared__ int nodebase[256];
    int b = blockIdx.x;
    int nbase = b << 8;
    int nn = min(256, N - nbase);
    int tid = threadIdx.x;
    int bucket_base = tscan[b * NBLK];
    int bucket_end  = tscan[(b + 1) * NBLK];

    deg[tid] = 0;
    __syncthreads();
    for (int i = bucket_base + tid; i < bucket_end; i += 256)
        atomicAdd(&deg[binned[i] >> 24], 1);
    __syncthreads();
    int v = deg[tid];
    sc[tid] = v;
    __syncthreads();
    for (int off = 1; off < 256; off <<= 1) {
        int t = (tid >= off) ? sc[tid - off] : 0;
        __syncthreads();
        sc[tid] += t;
        __syncthreads();
    }
    int excl = sc[tid] - v;
    nodebase[tid] = bucket_base + excl;
    if (tid < nn) {
        rowp[nbase + tid] = bucket_base + excl;
        dinv[nbase + tid] = rsqrtf((float)(v + 1));  // +1 self loop
    }
    if (nbase + nn == N && tid == 255) rowp[N] = bucket_base + sc[255];
    deg[tid] = 0;                       // reuse as cursor
    __syncthreads();
    for (int i = bucket_base + tid; i < bucket_end; i += 256) {
        unsigned int u = binned[i];
        int ld = u >> 24;
        int pos = nodebase[ld] + atomicAdd(&deg[ld], 1);
        csrc[pos] = (int)(u & 0xFFFFFFu);
    }
}

// ---------------- H(bf16) = dinv ⊙ (X @ W)  (K=64, fp32 VALU) ----------------
// 64x64 tile per block; 256 threads as 16x16; each thread: 4 rows x 4 cols (16 acc).
// k-loop unroll capped at 2 (R4: full unroll -> 256 VGPR; R3: forced cap -> spills).
// X input fp32 (xbf16=0) or bf16 (xbf16=1, staged->fp32 LDS; inner loop identical).
__global__ __launch_bounds__(256) void gemm64_kernel(const void* __restrict__ Xv,
                                                     const float* __restrict__ W,
                                                     const float* __restrict__ dscale,
                                                     unsigned short* __restrict__ H,
                                                     int nrows, int xbf16) {
    __shared__ float Xs[64 * XS_STRIDE];
    __shared__ float Ws[64 * 64];
    int tid = threadIdx.x;
    int row0 = blockIdx.x * 64;

    {
        const float4* W4 = (const float4*)W;
#pragma unroll
        for (int i = 0; i < 4; i++) {
            int idx = tid + 256 * i;
            float4 v = W4[idx];
            int r = idx >> 4, kc = (idx & 15) << 2;
            *(float4*)&Ws[r * 64 + kc] = v;
        }
    }
    if (xbf16) {
        const unsigned short* Xh = (const unsigned short*)Xv + (size_t)row0 * NCH;
#pragma unroll
        for (int i = 0; i < 2; i++) {
            int idx = tid + 256 * i;      // 16B unit = 8 bf16 channels
            int r = idx >> 3, kc = (idx & 7) << 3;
            if (row0 + r < nrows) {
                int4 v = *(const int4*)&Xh[r * NCH + kc];
                float* dp = &Xs[r * XS_STRIDE + kc];
                float4 lo, hi;
                lo.x = bf2f((unsigned short)((unsigned)v.x & 0xFFFF));
                lo.y = bf2f((unsigned short)((unsigned)v.x >> 16));
                lo.z = bf2f((unsigned short)((unsigned)v.y & 0xFFFF));
                lo.w = bf2f((unsigned short)((unsigned)v.y >> 16));
                hi.x = bf2f((unsigned short)((unsigned)v.z & 0xFFFF));
                hi.y = bf2f((unsigned short)((unsigned)v.z >> 16));
                hi.z = bf2f((unsigned short)((unsigned)v.w & 0xFFFF));
                hi.w = bf2f((unsigned short)((unsigned)v.w >> 16));
                *(float4*)&dp[0] = lo;     // (r*68+kc)%4==0 -> 16B aligned
                *(float4*)&dp[4] = hi;
            }
        }
    } else {
        const float4* X4 = (const float4*)((const float*)Xv + (size_t)row0 * NCH);
#pragma unroll
        for (int i = 0; i < 4; i++) {
            int idx = tid + 256 * i;
            int r = idx >> 4, kc = (idx & 15) << 2;
            if (row0 + r < nrows)
                *(float4*)&Xs[r * XS_STRIDE + kc] = X4[idx];
        }
    }
    __syncthreads();

    int c  = (tid & 15) << 2;
    int r0 = (tid >> 4) << 2;

    float4 acc[4];
#pragma unroll
    for (int i = 0; i < 4; i++) acc[i] = make_float4(0.f, 0.f, 0.f, 0.f);

#pragma unroll 2
    for (int k4 = 0; k4 < 16; k4++) {
        float4 wv[4], xv[4];
#pragma unroll
        for (int j = 0; j < 4; j++) wv[j] = *(const float4*)&Ws[(k4 * 4 + j) * 64 + c];
#pragma unroll
        for (int i = 0; i < 4; i++) xv[i] = *(const float4*)&Xs[(r0 + i) * XS_STRIDE + k4 * 4];
#pragma unroll
        for (int i = 0; i < 4; i++) {
            acc[i].x += xv[i].x * wv[0].x + xv[i].y * wv[1].x + xv[i].z * wv[2].x + xv[i].w * wv[3].x;
            acc[i].y += xv[i].x * wv[0].y + xv[i].y * wv[1].y + xv[i].z * wv[2].y + xv[i].w * wv[3].y;
            acc[i].z += xv[i].x * wv[0].z + xv[i].y * wv[1].z + xv[i].z * wv[2].z + xv[i].w * wv[3].z;
            acc[i].w += xv[i].x * wv[0].w + xv[i].y * wv[1].w + xv[i].z * wv[2].w + xv[i].w * wv[3].w;
        }
    }

#pragma unroll
    for (int i = 0; i < 4; i++) {
        int row = row0 + r0 + i;
        if (row < nrows) {
            float ds = dscale[row];
            ushort4 o;
            o.x = f2bf(acc[i].x * ds);
            o.y = f2bf(acc[i].y * ds);
            o.z = f2bf(acc[i].z * ds);
            o.w = f2bf(acc[i].w * ds);
            *(ushort4*)&H[(size_t)row * NCH + c] = o;   // 8 B aligned (c%4==0)
        }
    }
}

// ---------------- gather-aggregate: wave per node, lane = CHANNEL PAIR -------------
// Half-wave 0 handles even-slot edges, half-wave 1 odd-slot: each load instruction
// fetches TWO rows (2x bytes/instr vs R10). Cross-half shfl_xor(32) reduce.
// mode 0: write fp32 to outf. mode 1: relu + write bf16 to outh.
__global__ __launch_bounds__(256) void aggregate_kernel(const unsigned short* __restrict__ H,
                                                        const int* __restrict__ rowp,
                                                        const int* __restrict__ csrc,
                                                        const float* __restrict__ dinv,
                                                        const float* __restrict__ bias,
                                                        float* __restrict__ outf,
                                                        unsigned short* __restrict__ outh,
                                                        int n, int mode) {
    int node = blockIdx.x * 4 + (threadIdx.x >> 6);
    int lane = threadIdx.x & 63;
    if (node >= n) return;
    int hf = lane >> 5;          // half: 0 or 1
    int cb = (lane & 31) << 1;   // channel pair base
    float ax0 = 0.f, ay0 = 0.f, ax1 = 0.f, ay1 = 0.f;
    float ax2 = 0.f, ay2 = 0.f, ax3 = 0.f, ay3 = 0.f;
    if (hf == 0) {               // self loop counted once
        unsigned int u = *(const unsigned int*)&H[(size_t)node * NCH + cb];
        ax0 = bf2f((unsigned short)(u & 0xFFFF));
        ay0 = bf2f((unsigned short)(u >> 16));
    }
    int e = rowp[node];
    int end = rowp[node + 1];
    for (; e + 7 < end; e += 8) {        // 8 edges: half hf takes e+4*hf..+3
        int b0 = csrc[e + 4 * hf + 0];
        int b1 = csrc[e + 4 * hf + 1];
        int b2 = csrc[e + 4 * hf + 2];
        int b3 = csrc[e + 4 * hf + 3];
        unsigned int u0 = *(const unsigned int*)&H[(size_t)b0 * NCH + cb];
        unsigned int u1 = *(const unsigned int*)&H[(size_t)b1 * NCH + cb];
        unsigned int u2 = *(const unsigned int*)&H[(size_t)b2 * NCH + cb];
        unsigned int u3 = *(const unsigned int*)&H[(size_t)b3 * NCH + cb];
        ax0 += bf2f((unsigned short)(u0 & 0xFFFF)); ay0 += bf2f((unsigned short)(u0 >> 16));
        ax1 += bf2f((unsigned short)(u1 & 0xFFFF)); ay1 += bf2f((unsigned short)(u1 >> 16));
        ax2 += bf2f((unsigned short)(u2 & 0xFFFF)); ay2 += bf2f((unsigned short)(u2 >> 16));
        ax3 += bf2f((unsigned short)(u3 & 0xFFFF)); ay3 += bf2f((unsigned short)(u3 >> 16));
    }
    if (e + 3 < end) {                    // 4 edges: half hf takes e+2*hf, +1
        int b0 = csrc[e + 2 * hf + 0];
        int b1 = csrc[e + 2 * hf + 1];
        unsigned int u0 = *(const unsigned int*)&H[(size_t)b0 * NCH + cb];
        unsigned int u1 = *(const unsigned int*)&H[(size_t)b1 * NCH + cb];
        ax0 += bf2f((unsigned short)(u0 & 0xFFFF)); ay0 += bf2f((unsigned short)(u0 >> 16));
        ax1 += bf2f((unsigned short)(u1 & 0xFFFF)); ay1 += bf2f((unsigned short)(u1 >> 16));
        e += 4;
    }
    for (; e < end; e += 2) {             // pairs: half hf takes e+hf if in range
        int idx = e + hf;
        if (idx < end) {
            unsigned int u = *(const unsigned int*)&H[(size_t)csrc[idx] * NCH + cb];
            ax0 += bf2f((unsigned short)(u & 0xFFFF));
            ay0 += bf2f((unsigned short)(u >> 16));
        }
    }
    float sx = (ax0 + ax1) + (ax2 + ax3);
    float sy = (ay0 + ay1) + (ay2 + ay3);
    sx += __shfl_xor(sx, 32, 64);         // combine halves (same channel pair)
    sy += __shfl_xor(sy, 32, 64);
    if (hf == 0) {
        float di = dinv[node];
        float2 bv = *(const float2*)&bias[cb];
        float ox = bv.x + di * sx;
        float oy = bv.y + di * sy;
        if (mode) {                        // relu + bf16 activation
            ox = fmaxf(ox, 0.f); oy = fmaxf(oy, 0.f);
            unsigned int pk = (unsigned int)f2bf(ox) | ((unsigned int)f2bf(oy) << 16);
            *(unsigned int*)&outh[(size_t)node * NCH + cb] = pk;
        } else {
            *(float2*)&outf[(size_t)node * NCH + cb] = make_float2(ox, oy);
        }
    }
}

extern "C" void kernel_launch(void* const* d_in, const int* in_sizes, int n_in,
                              void* d_out, int out_size, void* d_ws, size_t ws_size,
                              hipStream_t stream) {
    const float* x  = (const float*)d_in[0];
    const int* edge = (const int*)d_in[1];
    const float* W1 = (const float*)d_in[2];
    const float* b1 = (const float*)d_in[3];
    const float* W2 = (const float*)d_in[4];
    const float* b2 = (const float*)d_in[5];
    float* out = (float*)d_out;

    const int N = in_sizes[0] / NCH;       // 100000
    const int E = in_sizes[1] / 2;         // 1200000
    const int* src = edge;
    const int* dst = edge + E;

    const int nbin = (N + 255) >> 8;       // 391
    const int NT   = nbin * NBLK;          // 100096 table entries

    // workspace layout (16B-aligned blocks); every word used is written each call.
    char* w = (char*)d_ws;
    const size_t SZT = 401408;             // >= (NT+1)*4
    const size_t SZN = 400896;             // >= (N+1)*4
    int*   table  = (int*)(w + 0);                 // NT ints
    int*   tscan  = (int*)(w + SZT);               // NT+1 ints
    int*   rowp   = (int*)(w + 2 * SZT);           // N+1 ints
    float* dinv   = (float*)(w + 2 * SZT + SZN);   // N floats
    int*   bsums  = (int*)(w + 2 * SZT + 2 * SZN); // 128 ints
    unsigned int* binned = (unsigned int*)(w + 2 * SZT + 2 * SZN + 512);   // E uints
    int*   csrc   = (int*)(w + 2 * SZT + 2 * SZN + 512 + (size_t)E * 4);   // E ints
    unsigned short* h   = (unsigned short*)(w + 2 * SZT + 2 * SZN + 512 + (size_t)E * 8); // N*64 bf16
    unsigned short* act = h + (size_t)N * NCH;                             // N*64 bf16

    const int NB_SCAN_T = (NT + 1023) / 1024;   // 98

    // CSR build (atomic-free at global scope)
    bhist_kernel<<<NBLK, 256, 0, stream>>>(dst, table, E, nbin);
    scanA_kernel<<<NB_SCAN_T, 256, 0, stream>>>(table, tscan, bsums, NT);
    scanB_kernel<<<1, 128, 0, stream>>>(bsums, NB_SCAN_T);
    scanC_kernel<<<(NT + 255) / 256, 256, 0, stream>>>(tscan, bsums, NT);
    bscat_kernel<<<NBLK, 256, 0, stream>>>(src, dst, tscan, binned, E, nbin);
    bfine_kernel<<<nbin, 256, 0, stream>>>(binned, tscan, rowp, dinv, csrc, N, nbin);

    const int GB = (N + 63) / 64;      // gemm blocks (64 rows each)
    const int AB = (N + 3) / 4;        // aggregate blocks (4 waves/block)

    // Layer 1: h = bf16(dinv ⊙ (x@W1)) ; act = bf16(relu(b1 + dinv ⊙ gather-sum(h)))
    gemm64_kernel<<<GB, 256, 0, stream>>>(x, W1, dinv, h, N, 0);
    aggregate_kernel<<<AB, 256, 0, stream>>>(h, rowp, csrc, dinv, b1, nullptr, act, N, 1);
    // Layer 2: h = bf16(dinv ⊙ (act@W2)) ; d_out = b2 + dinv ⊙ gather-sum(h)  (fp32)
    gemm64_kernel<<<GB, 256, 0, stream>>>(act, W2, dinv, h, N, 1);
    aggregate_kernel<<<AB, 256, 0, stream>>>(h, rowp, csrc, dinv, b2, out, nullptr, N, 0);
}

// Round 12
// 227.479 us; speedup vs baseline: 5.1035x; 1.1156x over previous
//
#include <hip/hip_runtime.h>

// GCN 2-layer: per layer h = X@W; out[i] = b + dinv[i]^2*h[i] + sum_{e:dst=i} dinv[src]*dinv[i]*h[src]
// N=100000 nodes, E=1200000 edges, C=64 channels.
// Kept: dinv[src] folded into gemm epilogue; dinv[dst] applied once in aggregate;
//       atomic-free multisplit CSR build (R9); bf16 H + bf16 inter-layer act (R10/11);
//       pair-channel lanes, half-wave per edge slot (R11).
// R12: aggregate restructured as ONE predicated batch-16 gather loop. R10/R11
//      evidence: halving traffic (R10) and halving instructions (R11) both left
//      dur at ~49 us -> latency-bound: one node/wave x ~18.6 wave generations,
//      5-6 serialized drain epochs per node. Batch-16 with clamped indices makes
//      84% of nodes (deg<=16) take one csrc-epoch + one H-epoch; multi-batch
//      iterations are index-independent and pipeline. Also: scanC dispatch folded
//      into bscat/bfine via pref(idx) = bsums[idx>>10] + (idx&1023 ? tscan[idx] : 0).

#define NCH 64
#define XS_STRIDE 68   // 64 + 4 pad: keeps b128 16B alignment; 2-way conflicts only (free)
#define NBLK 256       // partition blocks; chunk = ceil(E/NBLK)
#define NBIN_MAX 512   // LDS array bound; runtime nbin = ceil(N/256) = 391

static __device__ __forceinline__ unsigned short f2bf(float f) {
    unsigned int u = __float_as_uint(f);
    unsigned int r = (u + 0x7FFFu + ((u >> 16) & 1u)) >> 16;  // round-to-nearest-even
    return (unsigned short)r;
}
static __device__ __forceinline__ float bf2f(unsigned short h) {
    return __uint_as_float(((unsigned int)h) << 16);
}

// ---------------- exclusive scan phases A/B (C folded into consumers) --------------
__global__ __launch_bounds__(256) void scanA_kernel(const int* __restrict__ counts,
                                                    int* __restrict__ outp,
                                                    int* __restrict__ bsums, int n) {
    __shared__ int sh[256];
    int tid = threadIdx.x;
    int base = blockIdx.x * 1024;
    int v[4];
    int ts = 0;
#pragma unroll
    for (int j = 0; j < 4; j++) {
        int idx = base + tid * 4 + j;
        int c = (idx < n) ? counts[idx] : 0;
        v[j] = c; ts += c;
    }
    sh[tid] = ts; __syncthreads();
    for (int off = 1; off < 256; off <<= 1) {
        int t = (tid >= off) ? sh[tid - off] : 0;
        __syncthreads();
        sh[tid] += t;
        __syncthreads();
    }
    int run = sh[tid] - ts;
#pragma unroll
    for (int j = 0; j < 4; j++) {
        run += v[j];
        int idx = base + tid * 4 + j;
        if (idx < n) outp[idx + 1] = run;   // within-chunk inclusive through idx
    }
    if (tid == 255) bsums[blockIdx.x] = sh[255];
}

__global__ __launch_bounds__(128) void scanB_kernel(int* __restrict__ bsums, int nb) {
    __shared__ int sh[128];
    int tid = threadIdx.x;
    int v = (tid < nb) ? bsums[tid] : 0;
    sh[tid] = v; __syncthreads();
    for (int off = 1; off < 128; off <<= 1) {
        int t = (tid >= off) ? sh[tid - off] : 0;
        __syncthreads();
        sh[tid] += t;
        __syncthreads();
    }
    if (tid < nb) bsums[tid] = sh[tid] - v;   // exclusive chunk offsets
}

// global exclusive prefix at idx, from scanA partials + scanB chunk offsets
static __device__ __forceinline__ int pref(const int* __restrict__ tscan,
                                           const int* __restrict__ bsums, int idx) {
    int c = idx >> 10, r = idx & 1023;
    int t = r ? tscan[idx] : 0;
    return bsums[c] + t;
}

// ---------------- phase 1: per-block bucket histogram (LDS only) ----------------
__global__ __launch_bounds__(256) void bhist_kernel(const int* __restrict__ dst,
                                                    int* __restrict__ table,
                                                    int E, int nbin) {
    __shared__ int hb[NBIN_MAX];
    int blk = blockIdx.x;
    for (int i = threadIdx.x; i < nbin; i += 256) hb[i] = 0;
    __syncthreads();
    int chunk = (E + NBLK - 1) / NBLK;
    int e0 = blk * chunk, e1 = min(e0 + chunk, E);
    for (int e = e0 + threadIdx.x; e < e1; e += 256)
        atomicAdd(&hb[dst[e] >> 8], 1);
    __syncthreads();
    for (int i = threadIdx.x; i < nbin; i += 256)
        table[i * NBLK + blk] = hb[i];   // bin-major: scan order = (bin, blk)
}

// ---------------- phase 3: ranked scatter into bucket-grouped 'binned' ----------
__global__ __launch_bounds__(256) void bscat_kernel(const int* __restrict__ src,
                                                    const int* __restrict__ dst,
                                                    const int* __restrict__ tscan,
                                                    const int* __restrict__ bsums,
                                                    unsigned int* __restrict__ binned,
                                                    int E, int nbin) {
    __shared__ int base[NBIN_MAX];
    __shared__ int cur[NBIN_MAX];
    int blk = blockIdx.x;
    for (int i = threadIdx.x; i < nbin; i += 256) {
        base[i] = pref(tscan, bsums, i * NBLK + blk);
        cur[i] = 0;
    }
    __syncthreads();
    int chunk = (E + NBLK - 1) / NBLK;
    int e0 = blk * chunk, e1 = min(e0 + chunk, E);
    for (int e = e0 + threadIdx.x; e < e1; e += 256) {
        int d = dst[e];
        int b = d >> 8;
        int r = atomicAdd(&cur[b], 1);   // LDS atomic, ~12 hits/address
        binned[base[b] + r] = ((unsigned int)(d & 255) << 24) | (unsigned int)src[e];
    }
}

// ---------------- phase 4: per-bucket fine pass -> rowp, dinv, csrc ----------------
__global__ __launch_bounds__(256) void bfine_kernel(const unsigned int* __restrict__ binned,
                                                    const int* __restrict__ tscan,
                                                    const int* __restrict__ bsums,
                                                    int* __restrict__ rowp,
                                                    float* __restrict__ dinv,
                                                    int* __restrict__ csrc,
                                                    int N, int nbin) {
    __shared__ int deg[256];
    __shared__ int sc[256];
    __shared__ int nodebase[256];
    int b = blockIdx.x;
    int nbase = b << 8;
    int nn = min(256, N - nbase);
    int tid = threadIdx.x;
    int bucket_base = pref(tscan, bsums, b * NBLK);
    int bucket_end  = pref(tscan, bsums, (b + 1) * NBLK);

    deg[tid] = 0;
    __syncthreads();
    for (int i = bucket_base + tid; i < bucket_end; i += 256)
        atomicAdd(&deg[binned[i] >> 24], 1);
    __syncthreads();
    int v = deg[tid];
    sc[tid] = v;
    __syncthreads();
    for (int off = 1; off < 256; off <<= 1) {
        int t = (tid >= off) ? sc[tid - off] : 0;
        __syncthreads();
        sc[tid] += t;
        __syncthreads();
    }
    int excl = sc[tid] - v;
    nodebase[tid] = bucket_base + excl;
    if (tid < nn) {
        rowp[nbase + tid] = bucket_base + excl;
        dinv[nbase + tid] = rsqrtf((float)(v + 1));  // +1 self loop
    }
    if (nbase + nn == N && tid == 255) rowp[N] = bucket_base + sc[255];
    deg[tid] = 0;                       // reuse as cursor
    __syncthreads();
    for (int i = bucket_base + tid; i < bucket_end; i += 256) {
        unsigned int u = binned[i];
        int ld = u >> 24;
        int pos = nodebase[ld] + atomicAdd(&deg[ld], 1);
        csrc[pos] = (int)(u & 0xFFFFFFu);
    }
}

// ---------------- H(bf16) = dinv ⊙ (X @ W)  (K=64, fp32 VALU) ----------------
// 64x64 tile per block; 256 threads as 16x16; each thread: 4 rows x 4 cols (16 acc).
// k-loop unroll capped at 2 (R4: full unroll -> 256 VGPR; R3: forced cap -> spills).
// X input fp32 (xbf16=0) or bf16 (xbf16=1, staged->fp32 LDS; inner loop identical).
__global__ __launch_bounds__(256) void gemm64_kernel(const void* __restrict__ Xv,
                                                     const float* __restrict__ W,
                                                     const float* __restrict__ dscale,
                                                     unsigned short* __restrict__ H,
                                                     int nrows, int xbf16) {
    __shared__ float Xs[64 * XS_STRIDE];
    __shared__ float Ws[64 * 64];
    int tid = threadIdx.x;
    int row0 = blockIdx.x * 64;

    {
        const float4* W4 = (const float4*)W;
#pragma unroll
        for (int i = 0; i < 4; i++) {
            int idx = tid + 256 * i;
            float4 v = W4[idx];
            int r = idx >> 4, kc = (idx & 15) << 2;
            *(float4*)&Ws[r * 64 + kc] = v;
        }
    }
    if (xbf16) {
        const unsigned short* Xh = (const unsigned short*)Xv + (size_t)row0 * NCH;
#pragma unroll
        for (int i = 0; i < 2; i++) {
            int idx = tid + 256 * i;      // 16B unit = 8 bf16 channels
            int r = idx >> 3, kc = (idx & 7) << 3;
            if (row0 + r < nrows) {
                int4 v = *(const int4*)&Xh[r * NCH + kc];
                float* dp = &Xs[r * XS_STRIDE + kc];
                float4 lo, hi;
                lo.x = bf2f((unsigned short)((unsigned)v.x & 0xFFFF));
                lo.y = bf2f((unsigned short)((unsigned)v.x >> 16));
                lo.z = bf2f((unsigned short)((unsigned)v.y & 0xFFFF));
                lo.w = bf2f((unsigned short)((unsigned)v.y >> 16));
                hi.x = bf2f((unsigned short)((unsigned)v.z & 0xFFFF));
                hi.y = bf2f((unsigned short)((unsigned)v.z >> 16));
                hi.z = bf2f((unsigned short)((unsigned)v.w & 0xFFFF));
                hi.w = bf2f((unsigned short)((unsigned)v.w >> 16));
                *(float4*)&dp[0] = lo;     // (r*68+kc)%4==0 -> 16B aligned
                *(float4*)&dp[4] = hi;
            }
        }
    } else {
        const float4* X4 = (const float4*)((const float*)Xv + (size_t)row0 * NCH);
#pragma unroll
        for (int i = 0; i < 4; i++) {
            int idx = tid + 256 * i;
            int r = idx >> 4, kc = (idx & 15) << 2;
            if (row0 + r < nrows)
                *(float4*)&Xs[r * XS_STRIDE + kc] = X4[idx];
        }
    }
    __syncthreads();

    int c  = (tid & 15) << 2;
    int r0 = (tid >> 4) << 2;

    float4 acc[4];
#pragma unroll
    for (int i = 0; i < 4; i++) acc[i] = make_float4(0.f, 0.f, 0.f, 0.f);

#pragma unroll 2
    for (int k4 = 0; k4 < 16; k4++) {
        float4 wv[4], xv[4];
#pragma unroll
        for (int j = 0; j < 4; j++) wv[j] = *(const float4*)&Ws[(k4 * 4 + j) * 64 + c];
#pragma unroll
        for (int i = 0; i < 4; i++) xv[i] = *(const float4*)&Xs[(r0 + i) * XS_STRIDE + k4 * 4];
#pragma unroll
        for (int i = 0; i < 4; i++) {
            acc[i].x += xv[i].x * wv[0].x + xv[i].y * wv[1].x + xv[i].z * wv[2].x + xv[i].w * wv[3].x;
            acc[i].y += xv[i].x * wv[0].y + xv[i].y * wv[1].y + xv[i].z * wv[2].y + xv[i].w * wv[3].y;
            acc[i].z += xv[i].x * wv[0].z + xv[i].y * wv[1].z + xv[i].z * wv[2].z + xv[i].w * wv[3].z;
            acc[i].w += xv[i].x * wv[0].w + xv[i].y * wv[1].w + xv[i].z * wv[2].w + xv[i].w * wv[3].w;
        }
    }

#pragma unroll
    for (int i = 0; i < 4; i++) {
        int row = row0 + r0 + i;
        if (row < nrows) {
            float ds = dscale[row];
            ushort4 o;
            o.x = f2bf(acc[i].x * ds);
            o.y = f2bf(acc[i].y * ds);
            o.z = f2bf(acc[i].z * ds);
            o.w = f2bf(acc[i].w * ds);
            *(ushort4*)&H[(size_t)row * NCH + c] = o;   // 8 B aligned (c%4==0)
        }
    }
}

// ---------------- gather-aggregate: wave/node, lane = channel pair ------------------
// ONE predicated batch-16 loop (8 slots per half-wave, indices clamped to end-1,
// invalid slots masked at accumulate). Self row loaded before the loop (overlaps).
// Batches are index-independent -> multi-batch nodes pipeline.
// mode 0: write fp32 to outf. mode 1: relu + write bf16 to outh.
__global__ __launch_bounds__(256) void aggregate_kernel(const unsigned short* __restrict__ H,
                                                        const int* __restrict__ rowp,
                                                        const int* __restrict__ csrc,
                                                        const float* __restrict__ dinv,
                                                        const float* __restrict__ bias,
                                                        float* __restrict__ outf,
                                                        unsigned short* __restrict__ outh,
                                                        int n, int mode) {
    int node = blockIdx.x * 4 + (threadIdx.x >> 6);
    int lane = threadIdx.x & 63;
    if (node >= n) return;
    int hf = lane >> 5;          // half: 0 or 1
    int cb = (lane & 31) << 1;   // channel pair base

    int e0  = rowp[node];
    int end = rowp[node + 1];
    // self row (both halves load; half 0 accumulates) — issued before the edge loop
    unsigned int us = *(const unsigned int*)&H[(size_t)node * NCH + cb];
    float sx = 0.f, sy = 0.f;
    if (hf == 0) {
        sx = bf2f((unsigned short)(us & 0xFFFF));
        sy = bf2f((unsigned short)(us >> 16));
    }

    int last = end - 1;          // valid when end > e0 (loop guard covers deg==0)
    for (int base = e0; base < end; base += 16) {
        int s[8];
#pragma unroll
        for (int k = 0; k < 8; k++) {
            int j = base + 2 * k + hf;   // half 0: even slots, half 1: odd slots
            s[k] = csrc[min(j, last)];
        }
        unsigned int u[8];
#pragma unroll
        for (int k = 0; k < 8; k++)
            u[k] = *(const unsigned int*)&H[(size_t)s[k] * NCH + cb];
#pragma unroll
        for (int k = 0; k < 8; k++) {
            int j = base + 2 * k + hf;
            float fx = bf2f((unsigned short)(u[k] & 0xFFFF));
            float fy = bf2f((unsigned short)(u[k] >> 16));
            sx += (j < end) ? fx : 0.f;
            sy += (j < end) ? fy : 0.f;
        }
    }

    sx += __shfl_xor(sx, 32, 64);        // combine halves (same channel pair)
    sy += __shfl_xor(sy, 32, 64);
    if (hf == 0) {
        float di = dinv[node];
        float2 bv = *(const float2*)&bias[cb];
        float ox = bv.x + di * sx;
        float oy = bv.y + di * sy;
        if (mode) {                        // relu + bf16 activation
            ox = fmaxf(ox, 0.f); oy = fmaxf(oy, 0.f);
            unsigned int pk = (unsigned int)f2bf(ox) | ((unsigned int)f2bf(oy) << 16);
            *(unsigned int*)&outh[(size_t)node * NCH + cb] = pk;
        } else {
            *(float2*)&outf[(size_t)node * NCH + cb] = make_float2(ox, oy);
        }
    }
}

extern "C" void kernel_launch(void* const* d_in, const int* in_sizes, int n_in,
                              void* d_out, int out_size, void* d_ws, size_t ws_size,
                              hipStream_t stream) {
    const float* x  = (const float*)d_in[0];
    const int* edge = (const int*)d_in[1];
    const float* W1 = (const float*)d_in[2];
    const float* b1 = (const float*)d_in[3];
    const float* W2 = (const float*)d_in[4];
    const float* b2 = (const float*)d_in[5];
    float* out = (float*)d_out;

    const int N = in_sizes[0] / NCH;       // 100000
    const int E = in_sizes[1] / 2;         // 1200000
    const int* src = edge;
    const int* dst = edge + E;

    const int nbin = (N + 255) >> 8;       // 391
    const int NT   = nbin * NBLK;          // 100096 table entries

    // workspace layout (16B-aligned blocks); every word used is written each call.
    char* w = (char*)d_ws;
    const size_t SZT = 401408;             // >= (NT+1)*4
    const size_t SZN = 400896;             // >= (N+1)*4
    int*   table  = (int*)(w + 0);                 // NT ints
    int*   tscan  = (int*)(w + SZT);               // NT+1 ints
    int*   rowp   = (int*)(w + 2 * SZT);           // N+1 ints
    float* dinv   = (float*)(w + 2 * SZT + SZN);   // N floats
    int*   bsums  = (int*)(w + 2 * SZT + 2 * SZN); // 128 ints
    unsigned int* binned = (unsigned int*)(w + 2 * SZT + 2 * SZN + 512);   // E uints
    int*   csrc   = (int*)(w + 2 * SZT + 2 * SZN + 512 + (size_t)E * 4);   // E ints
    unsigned short* h   = (unsigned short*)(w + 2 * SZT + 2 * SZN + 512 + (size_t)E * 8); // N*64 bf16
    unsigned short* act = h + (size_t)N * NCH;                             // N*64 bf16

    const int NB_SCAN_T = (NT + 1023) / 1024;   // 98

    // CSR build (atomic-free at global scope; scanC folded into bscat/bfine)
    bhist_kernel<<<NBLK, 256, 0, stream>>>(dst, table, E, nbin);
    scanA_kernel<<<NB_SCAN_T, 256, 0, stream>>>(table, tscan, bsums, NT);
    scanB_kernel<<<1, 128, 0, stream>>>(bsums, NB_SCAN_T);
    bscat_kernel<<<NBLK, 256, 0, stream>>>(src, dst, tscan, bsums, binned, E, nbin);
    bfine_kernel<<<nbin, 256, 0, stream>>>(binned, tscan, bsums, rowp, dinv, csrc, N, nbin);

    const int GB = (N + 63) / 64;      // gemm blocks (64 rows each)
    const int AB = (N + 3) / 4;        // aggregate blocks (4 waves/block)

    // Layer 1: h = bf16(dinv ⊙ (x@W1)) ; act = bf16(relu(b1 + dinv ⊙ gather-sum(h)))
    gemm64_kernel<<<GB, 256, 0, stream>>>(x, W1, dinv, h, N, 0);
    aggregate_kernel<<<AB, 256, 0, stream>>>(h, rowp, csrc, dinv, b1, nullptr, act, N, 1);
    // Layer 2: h = bf16(dinv ⊙ (act@W2)) ; d_out = b2 + dinv ⊙ gather-sum(h)  (fp32)
    gemm64_kernel<<<GB, 256, 0, stream>>>(act, W2, dinv, h, N, 1);
    aggregate_kernel<<<AB, 256, 0, stream>>>(h, rowp, csrc, dinv, b2, out, nullptr, N, 0);
}

// Round 13
// 227.105 us; speedup vs baseline: 5.1119x; 1.0016x over previous
//
#include <hip/hip_runtime.h>

// GCN 2-layer: per layer h = X@W; out[i] = b + dinv[i]^2*h[i] + sum_{e:dst=i} dinv[src]*dinv[i]*h[src]
// N=100000 nodes, E=1200000 edges, C=64 channels.
// Kept: dinv[src] folded into gemm epilogue; dinv[dst] applied once in aggregate;
//       atomic-free multisplit CSR build (R9); bf16 H + bf16 inter-layer act (R10/11);
//       predicated batch-16 gather (R12: 49->36us, epochs are the bottleneck).
// R13: aggregate = ONE NODE PER 32-LANE HALF-WAVE (lane = channel pair, 32x4B =
//      full row). Per-instruction bytes unchanged (both halves' rows share each
//      wave instruction) but nodes/wave doubles -> wave generations 18.6 -> 9.3,
//      two independent latency chains interleave per wave, shfl_xor removed.
//      R11/R12 evidence: aggregate is latency-epoch-bound, not BW/issue-bound.

#define NCH 64
#define XS_STRIDE 68   // 64 + 4 pad: keeps b128 16B alignment; 2-way conflicts only (free)
#define NBLK 256       // partition blocks; chunk = ceil(E/NBLK)
#define NBIN_MAX 512   // LDS array bound; runtime nbin = ceil(N/256) = 391

static __device__ __forceinline__ unsigned short f2bf(float f) {
    unsigned int u = __float_as_uint(f);
    unsigned int r = (u + 0x7FFFu + ((u >> 16) & 1u)) >> 16;  // round-to-nearest-even
    return (unsigned short)r;
}
static __device__ __forceinline__ float bf2f(unsigned short h) {
    return __uint_as_float(((unsigned int)h) << 16);
}

// ---------------- exclusive scan phases A/B (C folded into consumers) --------------
__global__ __launch_bounds__(256) void scanA_kernel(const int* __restrict__ counts,
                                                    int* __restrict__ outp,
                                                    int* __restrict__ bsums, int n) {
    __shared__ int sh[256];
    int tid = threadIdx.x;
    int base = blockIdx.x * 1024;
    int v[4];
    int ts = 0;
#pragma unroll
    for (int j = 0; j < 4; j++) {
        int idx = base + tid * 4 + j;
        int c = (idx < n) ? counts[idx] : 0;
        v[j] = c; ts += c;
    }
    sh[tid] = ts; __syncthreads();
    for (int off = 1; off < 256; off <<= 1) {
        int t = (tid >= off) ? sh[tid - off] : 0;
        __syncthreads();
        sh[tid] += t;
        __syncthreads();
    }
    int run = sh[tid] - ts;
#pragma unroll
    for (int j = 0; j < 4; j++) {
        run += v[j];
        int idx = base + tid * 4 + j;
        if (idx < n) outp[idx + 1] = run;   // within-chunk inclusive through idx
    }
    if (tid == 255) bsums[blockIdx.x] = sh[255];
}

__global__ __launch_bounds__(128) void scanB_kernel(int* __restrict__ bsums, int nb) {
    __shared__ int sh[128];
    int tid = threadIdx.x;
    int v = (tid < nb) ? bsums[tid] : 0;
    sh[tid] = v; __syncthreads();
    for (int off = 1; off < 128; off <<= 1) {
        int t = (tid >= off) ? sh[tid - off] : 0;
        __syncthreads();
        sh[tid] += t;
        __syncthreads();
    }
    if (tid < nb) bsums[tid] = sh[tid] - v;   // exclusive chunk offsets
}

// global exclusive prefix at idx, from scanA partials + scanB chunk offsets
static __device__ __forceinline__ int pref(const int* __restrict__ tscan,
                                           const int* __restrict__ bsums, int idx) {
    int c = idx >> 10, r = idx & 1023;
    int t = r ? tscan[idx] : 0;
    return bsums[c] + t;
}

// ---------------- phase 1: per-block bucket histogram (LDS only) ----------------
__global__ __launch_bounds__(256) void bhist_kernel(const int* __restrict__ dst,
                                                    int* __restrict__ table,
                                                    int E, int nbin) {
    __shared__ int hb[NBIN_MAX];
    int blk = blockIdx.x;
    for (int i = threadIdx.x; i < nbin; i += 256) hb[i] = 0;
    __syncthreads();
    int chunk = (E + NBLK - 1) / NBLK;
    int e0 = blk * chunk, e1 = min(e0 + chunk, E);
    for (int e = e0 + threadIdx.x; e < e1; e += 256)
        atomicAdd(&hb[dst[e] >> 8], 1);
    __syncthreads();
    for (int i = threadIdx.x; i < nbin; i += 256)
        table[i * NBLK + blk] = hb[i];   // bin-major: scan order = (bin, blk)
}

// ---------------- phase 3: ranked scatter into bucket-grouped 'binned' ----------
__global__ __launch_bounds__(256) void bscat_kernel(const int* __restrict__ src,
                                                    const int* __restrict__ dst,
                                                    const int* __restrict__ tscan,
                                                    const int* __restrict__ bsums,
                                                    unsigned int* __restrict__ binned,
                                                    int E, int nbin) {
    __shared__ int base[NBIN_MAX];
    __shared__ int cur[NBIN_MAX];
    int blk = blockIdx.x;
    for (int i = threadIdx.x; i < nbin; i += 256) {
        base[i] = pref(tscan, bsums, i * NBLK + blk);
        cur[i] = 0;
    }
    __syncthreads();
    int chunk = (E + NBLK - 1) / NBLK;
    int e0 = blk * chunk, e1 = min(e0 + chunk, E);
    for (int e = e0 + threadIdx.x; e < e1; e += 256) {
        int d = dst[e];
        int b = d >> 8;
        int r = atomicAdd(&cur[b], 1);   // LDS atomic, ~12 hits/address
        binned[base[b] + r] = ((unsigned int)(d & 255) << 24) | (unsigned int)src[e];
    }
}

// ---------------- phase 4: per-bucket fine pass -> rowp, dinv, csrc ----------------
__global__ __launch_bounds__(256) void bfine_kernel(const unsigned int* __restrict__ binned,
                                                    const int* __restrict__ tscan,
                                                    const int* __restrict__ bsums,
                                                    int* __restrict__ rowp,
                                                    float* __restrict__ dinv,
                                                    int* __restrict__ csrc,
                                                    int N, int nbin) {
    __shared__ int deg[256];
    __shared__ int sc[256];
    __shared__ int nodebase[256];
    int b = blockIdx.x;
    int nbase = b << 8;
    int nn = min(256, N - nbase);
    int tid = threadIdx.x;
    int bucket_base = pref(tscan, bsums, b * NBLK);
    int bucket_end  = pref(tscan, bsums, (b + 1) * NBLK);

    deg[tid] = 0;
    __syncthreads();
    for (int i = bucket_base + tid; i < bucket_end; i += 256)
        atomicAdd(&deg[binned[i] >> 24], 1);
    __syncthreads();
    int v = deg[tid];
    sc[tid] = v;
    __syncthreads();
    for (int off = 1; off < 256; off <<= 1) {
        int t = (tid >= off) ? sc[tid - off] : 0;
        __syncthreads();
        sc[tid] += t;
        __syncthreads();
    }
    int excl = sc[tid] - v;
    nodebase[tid] = bucket_base + excl;
    if (tid < nn) {
        rowp[nbase + tid] = bucket_base + excl;
        dinv[nbase + tid] = rsqrtf((float)(v + 1));  // +1 self loop
    }
    if (nbase + nn == N && tid == 255) rowp[N] = bucket_base + sc[255];
    deg[tid] = 0;                       // reuse as cursor
    __syncthreads();
    for (int i = bucket_base + tid; i < bucket_end; i += 256) {
        unsigned int u = binned[i];
        int ld = u >> 24;
        int pos = nodebase[ld] + atomicAdd(&deg[ld], 1);
        csrc[pos] = (int)(u & 0xFFFFFFu);
    }
}

// ---------------- H(bf16) = dinv ⊙ (X @ W)  (K=64, fp32 VALU) ----------------
// 64x64 tile per block; 256 threads as 16x16; each thread: 4 rows x 4 cols (16 acc).
// k-loop unroll capped at 2 (R4: full unroll -> 256 VGPR; R3: forced cap -> spills).
// X input fp32 (xbf16=0) or bf16 (xbf16=1, staged->fp32 LDS; inner loop identical).
__global__ __launch_bounds__(256) void gemm64_kernel(const void* __restrict__ Xv,
                                                     const float* __restrict__ W,
                                                     const float* __restrict__ dscale,
                                                     unsigned short* __restrict__ H,
                                                     int nrows, int xbf16) {
    __shared__ float Xs[64 * XS_STRIDE];
    __shared__ float Ws[64 * 64];
    int tid = threadIdx.x;
    int row0 = blockIdx.x * 64;

    {
        const float4* W4 = (const float4*)W;
#pragma unroll
        for (int i = 0; i < 4; i++) {
            int idx = tid + 256 * i;
            float4 v = W4[idx];
            int r = idx >> 4, kc = (idx & 15) << 2;
            *(float4*)&Ws[r * 64 + kc] = v;
        }
    }
    if (xbf16) {
        const unsigned short* Xh = (const unsigned short*)Xv + (size_t)row0 * NCH;
#pragma unroll
        for (int i = 0; i < 2; i++) {
            int idx = tid + 256 * i;      // 16B unit = 8 bf16 channels
            int r = idx >> 3, kc = (idx & 7) << 3;
            if (row0 + r < nrows) {
                int4 v = *(const int4*)&Xh[r * NCH + kc];
                float* dp = &Xs[r * XS_STRIDE + kc];
                float4 lo, hi;
                lo.x = bf2f((unsigned short)((unsigned)v.x & 0xFFFF));
                lo.y = bf2f((unsigned short)((unsigned)v.x >> 16));
                lo.z = bf2f((unsigned short)((unsigned)v.y & 0xFFFF));
                lo.w = bf2f((unsigned short)((unsigned)v.y >> 16));
                hi.x = bf2f((unsigned short)((unsigned)v.z & 0xFFFF));
                hi.y = bf2f((unsigned short)((unsigned)v.z >> 16));
                hi.z = bf2f((unsigned short)((unsigned)v.w & 0xFFFF));
                hi.w = bf2f((unsigned short)((unsigned)v.w >> 16));
                *(float4*)&dp[0] = lo;     // (r*68+kc)%4==0 -> 16B aligned
                *(float4*)&dp[4] = hi;
            }
        }
    } else {
        const float4* X4 = (const float4*)((const float*)Xv + (size_t)row0 * NCH);
#pragma unroll
        for (int i = 0; i < 4; i++) {
            int idx = tid + 256 * i;
            int r = idx >> 4, kc = (idx & 15) << 2;
            if (row0 + r < nrows)
                *(float4*)&Xs[r * XS_STRIDE + kc] = X4[idx];
        }
    }
    __syncthreads();

    int c  = (tid & 15) << 2;
    int r0 = (tid >> 4) << 2;

    float4 acc[4];
#pragma unroll
    for (int i = 0; i < 4; i++) acc[i] = make_float4(0.f, 0.f, 0.f, 0.f);

#pragma unroll 2
    for (int k4 = 0; k4 < 16; k4++) {
        float4 wv[4], xv[4];
#pragma unroll
        for (int j = 0; j < 4; j++) wv[j] = *(const float4*)&Ws[(k4 * 4 + j) * 64 + c];
#pragma unroll
        for (int i = 0; i < 4; i++) xv[i] = *(const float4*)&Xs[(r0 + i) * XS_STRIDE + k4 * 4];
#pragma unroll
        for (int i = 0; i < 4; i++) {
            acc[i].x += xv[i].x * wv[0].x + xv[i].y * wv[1].x + xv[i].z * wv[2].x + xv[i].w * wv[3].x;
            acc[i].y += xv[i].x * wv[0].y + xv[i].y * wv[1].y + xv[i].z * wv[2].y + xv[i].w * wv[3].y;
            acc[i].z += xv[i].x * wv[0].z + xv[i].y * wv[1].z + xv[i].z * wv[2].z + xv[i].w * wv[3].z;
            acc[i].w += xv[i].x * wv[0].w + xv[i].y * wv[1].w + xv[i].z * wv[2].w + xv[i].w * wv[3].w;
        }
    }

#pragma unroll
    for (int i = 0; i < 4; i++) {
        int row = row0 + r0 + i;
        if (row < nrows) {
            float ds = dscale[row];
            ushort4 o;
            o.x = f2bf(acc[i].x * ds);
            o.y = f2bf(acc[i].y * ds);
            o.z = f2bf(acc[i].z * ds);
            o.w = f2bf(acc[i].w * ds);
            *(ushort4*)&H[(size_t)row * NCH + c] = o;   // 8 B aligned (c%4==0)
        }
    }
}

// ---------------- gather-aggregate: ONE NODE PER 32-LANE HALF-WAVE ------------------
// lane = channel pair (32 x 4 B = full 128 B bf16 row). Batch-16 predicated slots
// per half (deg<=16: one csrc-epoch + one H-epoch). Two independent chains per wave.
// mode 0: write fp32 to outf. mode 1: relu + write bf16 to outh.
__global__ __launch_bounds__(256) void aggregate_kernel(const unsigned short* __restrict__ H,
                                                        const int* __restrict__ rowp,
                                                        const int* __restrict__ csrc,
                                                        const float* __restrict__ dinv,
                                                        const float* __restrict__ bias,
                                                        float* __restrict__ outf,
                                                        unsigned short* __restrict__ outh,
                                                        int n, int mode) {
    int node = blockIdx.x * 8 + (threadIdx.x >> 5);   // 8 half-waves per block
    int lane = threadIdx.x & 31;
    if (node >= n) return;
    int cb = lane << 1;          // channel pair base

    int e0  = rowp[node];
    int end = rowp[node + 1];
    // self row — issued before the edge loop, overlaps csrc fetch
    unsigned int us = *(const unsigned int*)&H[(size_t)node * NCH + cb];
    float sx = bf2f((unsigned short)(us & 0xFFFF));
    float sy = bf2f((unsigned short)(us >> 16));

    int last = end - 1;          // valid when end > e0 (loop guard covers deg==0)
    for (int base = e0; base < end; base += 16) {
        int s[16];
#pragma unroll
        for (int k = 0; k < 16; k++)
            s[k] = csrc[min(base + k, last)];
        unsigned int u[16];
#pragma unroll
        for (int k = 0; k < 16; k++)
            u[k] = *(const unsigned int*)&H[(size_t)s[k] * NCH + cb];
#pragma unroll
        for (int k = 0; k < 16; k++) {
            float fx = bf2f((unsigned short)(u[k] & 0xFFFF));
            float fy = bf2f((unsigned short)(u[k] >> 16));
            sx += (base + k < end) ? fx : 0.f;
            sy += (base + k < end) ? fy : 0.f;
        }
    }

    float di = dinv[node];
    float2 bv = *(const float2*)&bias[cb];
    float ox = bv.x + di * sx;
    float oy = bv.y + di * sy;
    if (mode) {                        // relu + bf16 activation
        ox = fmaxf(ox, 0.f); oy = fmaxf(oy, 0.f);
        unsigned int pk = (unsigned int)f2bf(ox) | ((unsigned int)f2bf(oy) << 16);
        *(unsigned int*)&outh[(size_t)node * NCH + cb] = pk;
    } else {
        *(float2*)&outf[(size_t)node * NCH + cb] = make_float2(ox, oy);
    }
}

extern "C" void kernel_launch(void* const* d_in, const int* in_sizes, int n_in,
                              void* d_out, int out_size, void* d_ws, size_t ws_size,
                              hipStream_t stream) {
    const float* x  = (const float*)d_in[0];
    const int* edge = (const int*)d_in[1];
    const float* W1 = (const float*)d_in[2];
    const float* b1 = (const float*)d_in[3];
    const float* W2 = (const float*)d_in[4];
    const float* b2 = (const float*)d_in[5];
    float* out = (float*)d_out;

    const int N = in_sizes[0] / NCH;       // 100000
    const int E = in_sizes[1] / 2;         // 1200000
    const int* src = edge;
    const int* dst = edge + E;

    const int nbin = (N + 255) >> 8;       // 391
    const int NT   = nbin * NBLK;          // 100096 table entries

    // workspace layout (16B-aligned blocks); every word used is written each call.
    char* w = (char*)d_ws;
    const size_t SZT = 401408;             // >= (NT+1)*4
    const size_t SZN = 400896;             // >= (N+1)*4
    int*   table  = (int*)(w + 0);                 // NT ints
    int*   tscan  = (int*)(w + SZT);               // NT+1 ints
    int*   rowp   = (int*)(w + 2 * SZT);           // N+1 ints
    float* dinv   = (float*)(w + 2 * SZT + SZN);   // N floats
    int*   bsums  = (int*)(w + 2 * SZT + 2 * SZN); // 128 ints
    unsigned int* binned = (unsigned int*)(w + 2 * SZT + 2 * SZN + 512);   // E uints
    int*   csrc   = (int*)(w + 2 * SZT + 2 * SZN + 512 + (size_t)E * 4);   // E ints
    unsigned short* h   = (unsigned short*)(w + 2 * SZT + 2 * SZN + 512 + (size_t)E * 8); // N*64 bf16
    unsigned short* act = h + (size_t)N * NCH;                             // N*64 bf16

    const int NB_SCAN_T = (NT + 1023) / 1024;   // 98

    // CSR build (atomic-free at global scope; scanC folded into bscat/bfine)
    bhist_kernel<<<NBLK, 256, 0, stream>>>(dst, table, E, nbin);
    scanA_kernel<<<NB_SCAN_T, 256, 0, stream>>>(table, tscan, bsums, NT);
    scanB_kernel<<<1, 128, 0, stream>>>(bsums, NB_SCAN_T);
    bscat_kernel<<<NBLK, 256, 0, stream>>>(src, dst, tscan, bsums, binned, E, nbin);
    bfine_kernel<<<nbin, 256, 0, stream>>>(binned, tscan, bsums, rowp, dinv, csrc, N, nbin);

    const int GB = (N + 63) / 64;      // gemm blocks (64 rows each)
    const int AB = (N + 7) / 8;        // aggregate blocks (8 half-waves/block)

    // Layer 1: h = bf16(dinv ⊙ (x@W1)) ; act = bf16(relu(b1 + dinv ⊙ gather-sum(h)))
    gemm64_kernel<<<GB, 256, 0, stream>>>(x, W1, dinv, h, N, 0);
    aggregate_kernel<<<AB, 256, 0, stream>>>(h, rowp, csrc, dinv, b1, nullptr, act, N, 1);
    // Layer 2: h = bf16(dinv ⊙ (act@W2)) ; d_out = b2 + dinv ⊙ gather-sum(h)  (fp32)
    gemm64_kernel<<<GB, 256, 0, stream>>>(act, W2, dinv, h, N, 1);
    aggregate_kernel<<<AB, 256, 0, stream>>>(h, rowp, csrc, dinv, b2, out, nullptr, N, 0);
}